// Round 5
// baseline (318.856 us; speedup 1.0000x reference)
//
#include <hip/hip_runtime.h>

#define DM   2048
#define SEQ  2048
#define NB   2
#define NH   16
#define HD   128

typedef __bf16 bf16x8 __attribute__((ext_vector_type(8)));
typedef float f32x4 __attribute__((ext_vector_type(4)));
typedef unsigned short u16x4 __attribute__((ext_vector_type(4)));
typedef unsigned short u16x8 __attribute__((ext_vector_type(8)));

__device__ __forceinline__ unsigned short f2b(float f) {
  return __builtin_bit_cast(unsigned short, (__bf16)f);
}

__device__ __forceinline__ void gl_lds16(const void* g, void* l) {
  __builtin_amdgcn_global_load_lds(
      (const __attribute__((address_space(1))) void*)g,
      (__attribute__((address_space(3))) void*)l, 16, 0, 0);
}

// ---------------- kernel 1: x fp32 -> bf16 ----------------
__global__ void k_cvt_x(const float* __restrict__ x, unsigned short* __restrict__ xb) {
  int i = blockIdx.x * 256 + threadIdx.x;
  const float4* src = (const float4*)x + (size_t)i * 2;
  float4 a = src[0], c = src[1];
  u16x8 o;
  o[0] = f2b(a.x); o[1] = f2b(a.y); o[2] = f2b(a.z); o[3] = f2b(a.w);
  o[4] = f2b(c.x); o[5] = f2b(c.y); o[6] = f2b(c.z); o[7] = f2b(c.w);
  *((u16x8*)xb + i) = o;
}

// ---------------- kernel 2: W fp32 [K][N] -> bf16 Wt [N][K] ----------------
__global__ void k_cvt_w(const float* __restrict__ Wq, const float* __restrict__ Wk,
                        const float* __restrict__ Wv, unsigned short* __restrict__ wts) {
  const float* W = blockIdx.z == 0 ? Wq : (blockIdx.z == 1 ? Wk : Wv);
  unsigned short* out = wts + (size_t)blockIdx.z * DM * DM;
  __shared__ unsigned short t[64 * 68];  // t[col][row]
  int c0 = blockIdx.x * 64, r0 = blockIdx.y * 64;
  int tr = threadIdx.x >> 4, tc = (threadIdx.x & 15) * 4;
#pragma unroll
  for (int p = 0; p < 4; ++p) {
    int r = p * 16 + tr;
    float4 v = *(const float4*)(W + (size_t)(r0 + r) * DM + c0 + tc);
    t[(tc + 0) * 68 + r] = f2b(v.x);
    t[(tc + 1) * 68 + r] = f2b(v.y);
    t[(tc + 2) * 68 + r] = f2b(v.z);
    t[(tc + 3) * 68 + r] = f2b(v.w);
  }
  __syncthreads();
#pragma unroll
  for (int p = 0; p < 4; ++p) {
    int c = p * 16 + tr;
    u16x4 o = *(const u16x4*)&t[c * 68 + tc];
    *(u16x4*)(out + (size_t)(c0 + c) * DM + r0 + tc) = o;
  }
}

// ---------------- kernel 3: QKV GEMM, 128x256 tile, 2-phase 8-wave ----------------
#define NT_ 32

#define ST_A(T)                                                                \
  if ((T) < NT_) {                                                             \
    const int ktS = (T);                                                       \
    const unsigned ab_ = (ktS & 1) * 8192u;                                    \
    gl_lds16(Ag + (size_t)srow * DM + ktS * 64 + sgcol, &smem[ab_ + bo0]);     \
    gl_lds16(Ag + (size_t)(64 + srow) * DM + ktS * 64 + sgcol,                 \
             &smem[ab_ + 4096 + bo0]);                                         \
  }

#define ST_B1(T)                                                               \
  if ((T) < NT_) {                                                             \
    const int ktS = (T);                                                       \
    const unsigned bb_ = 16384u + (ktS & 1) * 16384u;                          \
    gl_lds16(Bg + (size_t)grB * DM + ktS * 64 + sgcol, &smem[bb_ + bo1]);      \
    gl_lds16(Bg + (size_t)(grB + 128) * DM + ktS * 64 + sgcol,                 \
             &smem[bb_ + 8192 + bo1]);                                         \
  }

#define ST_B2(T)                                                               \
  if ((T) < NT_) {                                                             \
    const int ktS = (T);                                                       \
    const unsigned bb_ = 16384u + (ktS & 1) * 16384u;                          \
    gl_lds16(Bg + (size_t)(grB + 32) * DM + ktS * 64 + sgcol,                  \
             &smem[bb_ + 2048 + bo1]);                                         \
    gl_lds16(Bg + (size_t)(grB + 160) * DM + ktS * 64 + sgcol,                 \
             &smem[bb_ + 10240 + bo1]);                                        \
  }

#define DS_A_ALL                                                               \
  {                                                                            \
    _Pragma("unroll") for (int mf_ = 0; mf_ < 4; ++mf_) {                      \
      int row_ = wr * 64 + mf_ * 16 + lr;                                      \
      _Pragma("unroll") for (int ks_ = 0; ks_ < 2; ++ks_)                      \
        af[mf_][ks_] = *(const bf16x8*)&smem[ab + row_ * 64 +                  \
                                             (((lg + ks_ * 4) ^ (lr & 7)) * 8)];\
    }                                                                          \
  }

#define DS_B(NF, J)                                                            \
  {                                                                            \
    int row_ = wc * 64 + (NF)*16 + lr;                                         \
    _Pragma("unroll") for (int ks_ = 0; ks_ < 2; ++ks_)                        \
      bfr[J][ks_] = *(const bf16x8*)&smem[bb + row_ * 64 +                     \
                                          (((lg + ks_ * 4) ^ (lr & 7)) * 8)];  \
  }

#define MFMA_P(NFB)                                                            \
  {                                                                            \
    _Pragma("unroll") for (int mf_ = 0; mf_ < 4; ++mf_)                        \
    _Pragma("unroll") for (int j_ = 0; j_ < 2; ++j_)                           \
    _Pragma("unroll") for (int ks_ = 0; ks_ < 2; ++ks_)                        \
      acc[mf_][(NFB) + j_] = __builtin_amdgcn_mfma_f32_16x16x32_bf16(          \
          af[mf_][ks_], bfr[j_][ks_], acc[mf_][(NFB) + j_], 0, 0, 0);          \
  }

__global__ __launch_bounds__(512, 2) void k_qkv(
    const unsigned short* __restrict__ xb, const unsigned short* __restrict__ wts,
    unsigned short* __restrict__ qb, unsigned short* __restrict__ kb,
    unsigned short* __restrict__ vtb) {
  __shared__ unsigned short smem[49152];

  const int id = blockIdx.x;
  const int swz = (id & 7) * 96 + (id >> 3);
  const int z = swz >> 8;
  const int rem = swz & 255;
  const int m0 = (rem >> 3) * 128;
  const int n0 = (rem & 7) * 256;

  const unsigned short* Ag = xb + (size_t)m0 * DM;
  const unsigned short* Bg = wts + (size_t)z * DM * DM + (size_t)n0 * DM;

  const int tid = threadIdx.x;
  const int wave = tid >> 6, lane = tid & 63;
  const int lr = lane & 15, lg = lane >> 4;
  const int wr = wave >> 2, wc = wave & 3;
  const int srow = tid >> 3;
  const int sgcol = ((tid & 7) ^ (srow & 7)) * 8;
  const int grB = srow + (srow & 32);
  const unsigned bo0 = wave * 512u;
  const unsigned bo1 = wave * 512u + ((wave & 4) << 9);

  f32x4 acc[4][4] = {};
  bf16x8 af[4][2], bfr[2][2];

  ST_A(0); ST_B1(0); ST_B2(0); ST_A(1); ST_B1(1);
  asm volatile("s_waitcnt vmcnt(4)" ::: "memory");
  __builtin_amdgcn_s_barrier();

  for (int t = 0; t < NT_; ++t) {
    const unsigned ab = (t & 1) * 8192u;
    const unsigned bb = 16384u + (t & 1) * 16384u;

    DS_A_ALL;
    DS_B(0, 0); DS_B(1, 1);
    ST_B2(t + 1);
    asm volatile("s_waitcnt lgkmcnt(8)" ::: "memory");
    __builtin_amdgcn_s_barrier();
    asm volatile("s_waitcnt lgkmcnt(0)" ::: "memory");
    __builtin_amdgcn_sched_barrier(0);
    __builtin_amdgcn_s_setprio(1);
    MFMA_P(0);
    __builtin_amdgcn_s_setprio(0);
    __builtin_amdgcn_s_barrier();

    DS_B(2, 0); DS_B(3, 1);
    ST_A(t + 2); ST_B1(t + 2);
    if (t < NT_ - 2)
      asm volatile("s_waitcnt vmcnt(4)" ::: "memory");
    else
      asm volatile("s_waitcnt vmcnt(0)" ::: "memory");
    __builtin_amdgcn_s_barrier();
    asm volatile("s_waitcnt lgkmcnt(0)" ::: "memory");
    __builtin_amdgcn_sched_barrier(0);
    __builtin_amdgcn_s_setprio(1);
    MFMA_P(2);
    __builtin_amdgcn_s_setprio(0);
    __builtin_amdgcn_s_barrier();
  }

  if (z < 2) {
    unsigned short* out = z == 0 ? qb : kb;
#pragma unroll
    for (int mf = 0; mf < 4; ++mf)
#pragma unroll
      for (int nf = 0; nf < 4; ++nf) {
        int n = n0 + wc * 64 + nf * 16 + lr;
        int h = n >> 7, d = n & 127;
#pragma unroll
        for (int r = 0; r < 4; ++r) {
          int m = m0 + wr * 64 + mf * 16 + lg * 4 + r;
          int b = m >> 11, s = m & 2047;
          out[(((size_t)(b * NH + h)) * SEQ + s) * HD + d] = f2b(acc[mf][nf][r]);
        }
      }
  } else {
#pragma unroll
    for (int mf = 0; mf < 4; ++mf)
#pragma unroll
      for (int nf = 0; nf < 4; ++nf) {
        int dl = wc * 64 + nf * 16 + lr;
        int g = wr * 16 + mf * 4 + lg;
        int gs = g ^ ((dl & 7) << 2);
        u16x4 pk = {f2b(acc[mf][nf][0]), f2b(acc[mf][nf][1]),
                    f2b(acc[mf][nf][2]), f2b(acc[mf][nf][3])};
        *(u16x4*)&smem[dl * 128 + gs * 4] = pk;
      }
    __builtin_amdgcn_s_barrier();
    asm volatile("s_waitcnt lgkmcnt(0)" ::: "memory");
    int b = m0 >> 11, sbase = m0 & 2047;
#pragma unroll
    for (int p = 0; p < 8; ++p) {
      int f = p * 512 + tid;
      int dl = f >> 4, c8 = f & 15;
      int g0 = (2 * c8) ^ ((dl & 7) << 2);
      u16x8 v = *(const u16x8*)&smem[dl * 128 + g0 * 4];
      int n = n0 + dl;
      int h = n >> 7, d = n & 127;
      *(u16x8*)(vtb + (((size_t)(b * NH + h)) * HD + d) * SEQ + sbase + c8 * 8) = v;
    }
  }
}

// ---------------- kernel 4: causal flash attention, latency-optimized ----------------
// 1024 blocks = 32 subtiles x 32 bh, heavy-first (LPT) + XCD swizzle.
// 4 waves x 16 q-rows. K staged (dbuf LDS, 32KB); V read directly from global/L2
// (early-issued, T14); P via per-wave LDS; defer-max (T13); setprio (T5).
__global__ __launch_bounds__(256, 3) void k_attn(
    const unsigned short* __restrict__ qb, const unsigned short* __restrict__ kb,
    const unsigned short* __restrict__ vtb, float* __restrict__ out) {
  __shared__ unsigned short Kl[2][64 * 128];   // [kv][d], swizzled
  __shared__ unsigned short Pl[4][16 * 72];    // per-wave [q][kv], pad 72

  const int id = blockIdx.x;
  const int swz = (id & 7) * 128 + (id >> 3);  // bijective over 1024
  const int bh = swz >> 5;                     // 4 consecutive bh per XCD chunk
  const int qt = 31 - (swz & 31);              // heavy-first within chunk
  const int q0 = qt * 64;
  const int b = bh >> 4, h = bh & 15;
  const int tid = threadIdx.x;
  const int wave = tid >> 6, lane = tid & 63;
  const int lr = lane & 15, lg = lane >> 4;

  const unsigned short* Qg = qb + (size_t)bh * SEQ * HD;
  const unsigned short* Vg = vtb + (size_t)bh * HD * SEQ;
  const float C = 0.12751744155229827f;  // (1/sqrt(128)) * log2(e)

  // per-thread staging constants (K only): 4 chunks of 16B
  const int srow0 = tid >> 4;            // rows 0..15 (+16p)
  const int ssc = (tid & 15) ^ (srow0 & 7);
  // running K pointer
  const unsigned short* Kt = kb + (size_t)bh * SEQ * HD;
  // V base: row = lr (+16*nf8), col = 8*lg (+32*ks2) + kv0(running)
  const unsigned short* Vt = Vg + (size_t)lr * SEQ + 8 * lg;

#define STAGE_K(BUF)                                                           \
  {                                                                            \
    _Pragma("unroll") for (int p = 0; p < 4; ++p) {                            \
      gl_lds16(Kt + (size_t)(p * 16 + srow0) * HD + ssc * 8,                   \
               &Kl[BUF][p * 2048 + tid * 8]);                                  \
    }                                                                          \
  }

  bf16x8 qf[4];
#pragma unroll
  for (int ks = 0; ks < 4; ++ks)
    qf[ks] = *(const bf16x8*)&Qg[(size_t)(q0 + wave * 16 + lr) * HD + ks * 32 + lg * 8];

  f32x4 oacc[8] = {};
  float mraw = -1e30f;
  float lsum = 0.f;

  STAGE_K(0);
  Kt += 64 * HD;
  asm volatile("s_waitcnt vmcnt(0)" ::: "memory");
  __syncthreads();

  for (int t = 0; t <= qt; ++t) {
    const int cur = t & 1;
    if (t < qt) {
      STAGE_K(cur ^ 1);
      Kt += 64 * HD;
    }

    // ---- QK^T (swapped): sacc[mf][r] = S[kv=16mf+4lg+r][q=lr] ----
    f32x4 sacc[4] = {};
    __builtin_amdgcn_s_setprio(1);
#pragma unroll
    for (int ks = 0; ks < 4; ++ks) {
      bf16x8 kf[4];
#pragma unroll
      for (int mf = 0; mf < 4; ++mf) {
        int row = mf * 16 + lr;
        kf[mf] = *(const bf16x8*)&Kl[cur][row * 128 + ((lg + ks * 4) ^ (row & 7)) * 8];
      }
#pragma unroll
      for (int mf = 0; mf < 4; ++mf)
        sacc[mf] = __builtin_amdgcn_mfma_f32_16x16x32_bf16(kf[mf], qf[ks], sacc[mf], 0, 0, 0);
    }
    __builtin_amdgcn_s_setprio(0);

    // ---- early-issue V loads, bundle 0 (ks2=0) ----
    bf16x8 vf0[8], vf1[8];
#pragma unroll
    for (int nf8 = 0; nf8 < 8; ++nf8)
      vf0[nf8] = *(const bf16x8*)(Vt + (size_t)nf8 * 16 * SEQ);

    if (t == qt) {  // diagonal tile: causal mask
      const int kv0 = t * 64;
#pragma unroll
      for (int mf = 0; mf < 4; ++mf)
#pragma unroll
        for (int r = 0; r < 4; ++r) {
          int kv = kv0 + mf * 16 + lg * 4 + r;
          int q = q0 + wave * 16 + lr;
          if (kv > q) sacc[mf][r] = -1e30f;
        }
    }

    // ---- row max (q = lr), 2 cross-lane hops ----
    float vm = fmaxf(fmaxf(fmaxf(sacc[0][0], sacc[0][1]), fmaxf(sacc[0][2], sacc[0][3])),
                     fmaxf(fmaxf(sacc[1][0], sacc[1][1]), fmaxf(sacc[1][2], sacc[1][3])));
    vm = fmaxf(vm,
               fmaxf(fmaxf(fmaxf(sacc[2][0], sacc[2][1]), fmaxf(sacc[2][2], sacc[2][3])),
                     fmaxf(fmaxf(sacc[3][0], sacc[3][1]), fmaxf(sacc[3][2], sacc[3][3]))));
    vm = fmaxf(vm, __shfl_xor(vm, 16));
    vm = fmaxf(vm, __shfl_xor(vm, 32));

    // ---- defer-max (T13): rescale only when some row grew > THR ----
    if (__any(vm - mraw > 60.0f)) {
      float nm = fmaxf(mraw, vm);
      float pfac = exp2f((mraw - nm) * C);
#pragma unroll
      for (int r = 0; r < 4; ++r) {
        float f = __shfl(pfac, lg * 4 + r);
#pragma unroll
        for (int nf8 = 0; nf8 < 8; ++nf8) oacc[nf8][r] *= f;
      }
      lsum *= pfac;
      mraw = nm;
    }
    const float mC = mraw * C;

    // ---- exp + pack P to LDS ----
#pragma unroll
    for (int mf = 0; mf < 4; ++mf) {
#pragma unroll
      for (int r = 0; r < 4; ++r) sacc[mf][r] = exp2f(sacc[mf][r] * C - mC);
      u16x4 pk = {f2b(sacc[mf][0]), f2b(sacc[mf][1]),
                  f2b(sacc[mf][2]), f2b(sacc[mf][3])};
      *(u16x4*)&Pl[wave][lr * 72 + mf * 16 + lg * 4] = pk;
    }

    // ---- early-issue V loads, bundle 1 (ks2=1) ----
#pragma unroll
    for (int nf8 = 0; nf8 < 8; ++nf8)
      vf1[nf8] = *(const bf16x8*)(Vt + (size_t)nf8 * 16 * SEQ + 32);
    Vt += 64;

    // ---- row sum (overlaps P write + V latency) ----
    float ssum = 0.f;
#pragma unroll
    for (int mf = 0; mf < 4; ++mf)
#pragma unroll
      for (int r = 0; r < 4; ++r) ssum += sacc[mf][r];
    ssum += __shfl_xor(ssum, 16);
    ssum += __shfl_xor(ssum, 32);
    lsum += ssum;

    // ---- O += P . V ----
    {
      bf16x8 pf0 = *(const bf16x8*)&Pl[wave][lr * 72 + lg * 8];
      bf16x8 pf1 = *(const bf16x8*)&Pl[wave][lr * 72 + 32 + lg * 8];
      __builtin_amdgcn_s_setprio(1);
#pragma unroll
      for (int nf8 = 0; nf8 < 8; ++nf8)
        oacc[nf8] = __builtin_amdgcn_mfma_f32_16x16x32_bf16(pf0, vf0[nf8], oacc[nf8], 0, 0, 0);
#pragma unroll
      for (int nf8 = 0; nf8 < 8; ++nf8)
        oacc[nf8] = __builtin_amdgcn_mfma_f32_16x16x32_bf16(pf1, vf1[nf8], oacc[nf8], 0, 0, 0);
      __builtin_amdgcn_s_setprio(0);
    }

    asm volatile("s_waitcnt vmcnt(0)" ::: "memory");  // K(t+1) staged
    __syncthreads();
  }

  // normalize + store fp32
#pragma unroll
  for (int r = 0; r < 4; ++r) {
    float li = 1.0f / __shfl(lsum, lg * 4 + r);
    int q = q0 + wave * 16 + lg * 4 + r;
    float* orow = out + ((size_t)b * SEQ + q) * DM + h * HD;
#pragma unroll
    for (int nf8 = 0; nf8 < 8; ++nf8)
      orow[nf8 * 16 + lr] = oacc[nf8][r] * li;
  }
}

// ---------------- launcher ----------------
extern "C" void kernel_launch(void* const* d_in, const int* in_sizes, int n_in,
                              void* d_out, int out_size, void* d_ws, size_t ws_size,
                              hipStream_t stream) {
  const float* x  = (const float*)d_in[0];
  const float* Wq = (const float*)d_in[1];
  const float* Wk = (const float*)d_in[2];
  const float* Wv = (const float*)d_in[3];
  float* out = (float*)d_out;
  char* ws = (char*)d_ws;

  unsigned short* xb  = (unsigned short*)(ws);              // 4096x2048 bf16   (16 MB)
  unsigned short* wt  = (unsigned short*)(ws + 16777216);   // 3x 2048x2048 bf16 (24 MB)
  unsigned short* qb  = (unsigned short*)(ws + 41943040);   // [32][2048][128]  (16 MB)
  unsigned short* kb  = (unsigned short*)(ws + 58720256);   // [32][2048][128]  (16 MB)
  unsigned short* vtb = (unsigned short*)(ws + 75497472);   // [32][128][2048]  (16 MB)

  k_cvt_x<<<4096, 256, 0, stream>>>(x, xb);
  dim3 gw(32, 32, 3);
  k_cvt_w<<<gw, 256, 0, stream>>>(Wq, Wk, Wv, wt);
  k_qkv<<<768, 512, 0, stream>>>(xb, wt, qb, kb, vtb);
  k_attn<<<1024, 256, 0, stream>>>(qb, kb, vtb, out);
}

// Round 6
// 236.386 us; speedup vs baseline: 1.3489x; 1.3489x over previous
//
#include <hip/hip_runtime.h>

#define DM   2048
#define SEQ  2048
#define NB   2
#define NH   16
#define HD   128

typedef __bf16 bf16x8 __attribute__((ext_vector_type(8)));
typedef float f32x4 __attribute__((ext_vector_type(4)));
typedef unsigned short u16x4 __attribute__((ext_vector_type(4)));
typedef unsigned short u16x8 __attribute__((ext_vector_type(8)));
typedef unsigned int u32x4 __attribute__((ext_vector_type(4)));

__device__ __forceinline__ unsigned short f2b(float f) {
  return __builtin_bit_cast(unsigned short, (__bf16)f);
}

__device__ __forceinline__ unsigned cvt_pk_bf16(float lo, float hi) {
  unsigned r;
  asm("v_cvt_pk_bf16_f32 %0, %1, %2" : "=v"(r) : "v"(lo), "v"(hi));
  return r;
}

__device__ __forceinline__ void gl_lds16(const void* g, void* l) {
  __builtin_amdgcn_global_load_lds(
      (const __attribute__((address_space(1))) void*)g,
      (__attribute__((address_space(3))) void*)l, 16, 0, 0);
}

// ---------------- kernel 1: x fp32 -> bf16 ----------------
__global__ void k_cvt_x(const float* __restrict__ x, unsigned short* __restrict__ xb) {
  int i = blockIdx.x * 256 + threadIdx.x;
  const float4* src = (const float4*)x + (size_t)i * 2;
  float4 a = src[0], c = src[1];
  u16x8 o;
  o[0] = f2b(a.x); o[1] = f2b(a.y); o[2] = f2b(a.z); o[3] = f2b(a.w);
  o[4] = f2b(c.x); o[5] = f2b(c.y); o[6] = f2b(c.z); o[7] = f2b(c.w);
  *((u16x8*)xb + i) = o;
}

// ---------------- kernel 2: W fp32 [K][N] -> bf16 Wt [N][K] ----------------
__global__ void k_cvt_w(const float* __restrict__ Wq, const float* __restrict__ Wk,
                        const float* __restrict__ Wv, unsigned short* __restrict__ wts) {
  const float* W = blockIdx.z == 0 ? Wq : (blockIdx.z == 1 ? Wk : Wv);
  unsigned short* out = wts + (size_t)blockIdx.z * DM * DM;
  __shared__ unsigned short t[64 * 68];  // t[col][row]
  int c0 = blockIdx.x * 64, r0 = blockIdx.y * 64;
  int tr = threadIdx.x >> 4, tc = (threadIdx.x & 15) * 4;
#pragma unroll
  for (int p = 0; p < 4; ++p) {
    int r = p * 16 + tr;
    float4 v = *(const float4*)(W + (size_t)(r0 + r) * DM + c0 + tc);
    t[(tc + 0) * 68 + r] = f2b(v.x);
    t[(tc + 1) * 68 + r] = f2b(v.y);
    t[(tc + 2) * 68 + r] = f2b(v.z);
    t[(tc + 3) * 68 + r] = f2b(v.w);
  }
  __syncthreads();
#pragma unroll
  for (int p = 0; p < 4; ++p) {
    int c = p * 16 + tr;
    u16x4 o = *(const u16x4*)&t[c * 68 + tc];
    *(u16x4*)(out + (size_t)(c0 + c) * DM + r0 + tc) = o;
  }
}

// ---------------- kernel 3: QKV GEMM, 128x256 tile, 2-phase 8-wave ----------------
#define NT_ 32

#define ST_A(T)                                                                \
  if ((T) < NT_) {                                                             \
    const int ktS = (T);                                                       \
    const unsigned ab_ = (ktS & 1) * 8192u;                                    \
    gl_lds16(Ag + (size_t)srow * DM + ktS * 64 + sgcol, &smem[ab_ + bo0]);     \
    gl_lds16(Ag + (size_t)(64 + srow) * DM + ktS * 64 + sgcol,                 \
             &smem[ab_ + 4096 + bo0]);                                         \
  }

#define ST_B1(T)                                                               \
  if ((T) < NT_) {                                                             \
    const int ktS = (T);                                                       \
    const unsigned bb_ = 16384u + (ktS & 1) * 16384u;                          \
    gl_lds16(Bg + (size_t)grB * DM + ktS * 64 + sgcol, &smem[bb_ + bo1]);      \
    gl_lds16(Bg + (size_t)(grB + 128) * DM + ktS * 64 + sgcol,                 \
             &smem[bb_ + 8192 + bo1]);                                         \
  }

#define ST_B2(T)                                                               \
  if ((T) < NT_) {                                                             \
    const int ktS = (T);                                                       \
    const unsigned bb_ = 16384u + (ktS & 1) * 16384u;                          \
    gl_lds16(Bg + (size_t)(grB + 32) * DM + ktS * 64 + sgcol,                  \
             &smem[bb_ + 2048 + bo1]);                                         \
    gl_lds16(Bg + (size_t)(grB + 160) * DM + ktS * 64 + sgcol,                 \
             &smem[bb_ + 10240 + bo1]);                                        \
  }

#define DS_A_ALL                                                               \
  {                                                                            \
    _Pragma("unroll") for (int mf_ = 0; mf_ < 4; ++mf_) {                      \
      int row_ = wr * 64 + mf_ * 16 + lr;                                      \
      _Pragma("unroll") for (int ks_ = 0; ks_ < 2; ++ks_)                      \
        af[mf_][ks_] = *(const bf16x8*)&smem[ab + row_ * 64 +                  \
                                             (((lg + ks_ * 4) ^ (lr & 7)) * 8)];\
    }                                                                          \
  }

#define DS_B(NF, J)                                                            \
  {                                                                            \
    int row_ = wc * 64 + (NF)*16 + lr;                                         \
    _Pragma("unroll") for (int ks_ = 0; ks_ < 2; ++ks_)                        \
      bfr[J][ks_] = *(const bf16x8*)&smem[bb + row_ * 64 +                     \
                                          (((lg + ks_ * 4) ^ (lr & 7)) * 8)];  \
  }

#define MFMA_P(NFB)                                                            \
  {                                                                            \
    _Pragma("unroll") for (int mf_ = 0; mf_ < 4; ++mf_)                        \
    _Pragma("unroll") for (int j_ = 0; j_ < 2; ++j_)                           \
    _Pragma("unroll") for (int ks_ = 0; ks_ < 2; ++ks_)                        \
      acc[mf_][(NFB) + j_] = __builtin_amdgcn_mfma_f32_16x16x32_bf16(          \
          af[mf_][ks_], bfr[j_][ks_], acc[mf_][(NFB) + j_], 0, 0, 0);          \
  }

__global__ __launch_bounds__(512, 2) void k_qkv(
    const unsigned short* __restrict__ xb, const unsigned short* __restrict__ wts,
    unsigned short* __restrict__ qb, unsigned short* __restrict__ kb,
    unsigned short* __restrict__ vtb) {
  __shared__ unsigned short smem[49152];

  const int id = blockIdx.x;
  const int swz = (id & 7) * 96 + (id >> 3);
  const int z = swz >> 8;
  const int rem = swz & 255;
  const int m0 = (rem >> 3) * 128;
  const int n0 = (rem & 7) * 256;

  const unsigned short* Ag = xb + (size_t)m0 * DM;
  const unsigned short* Bg = wts + (size_t)z * DM * DM + (size_t)n0 * DM;

  const int tid = threadIdx.x;
  const int wave = tid >> 6, lane = tid & 63;
  const int lr = lane & 15, lg = lane >> 4;
  const int wr = wave >> 2, wc = wave & 3;
  const int srow = tid >> 3;
  const int sgcol = ((tid & 7) ^ (srow & 7)) * 8;
  const int grB = srow + (srow & 32);
  const unsigned bo0 = wave * 512u;
  const unsigned bo1 = wave * 512u + ((wave & 4) << 9);

  f32x4 acc[4][4] = {};
  bf16x8 af[4][2], bfr[2][2];

  ST_A(0); ST_B1(0); ST_B2(0); ST_A(1); ST_B1(1);
  asm volatile("s_waitcnt vmcnt(4)" ::: "memory");
  __builtin_amdgcn_s_barrier();

  for (int t = 0; t < NT_; ++t) {
    const unsigned ab = (t & 1) * 8192u;
    const unsigned bb = 16384u + (t & 1) * 16384u;

    DS_A_ALL;
    DS_B(0, 0); DS_B(1, 1);
    ST_B2(t + 1);
    asm volatile("s_waitcnt lgkmcnt(8)" ::: "memory");
    __builtin_amdgcn_s_barrier();
    asm volatile("s_waitcnt lgkmcnt(0)" ::: "memory");
    __builtin_amdgcn_sched_barrier(0);
    __builtin_amdgcn_s_setprio(1);
    MFMA_P(0);
    __builtin_amdgcn_s_setprio(0);
    __builtin_amdgcn_s_barrier();

    DS_B(2, 0); DS_B(3, 1);
    ST_A(t + 2); ST_B1(t + 2);
    if (t < NT_ - 2)
      asm volatile("s_waitcnt vmcnt(4)" ::: "memory");
    else
      asm volatile("s_waitcnt vmcnt(0)" ::: "memory");
    __builtin_amdgcn_s_barrier();
    asm volatile("s_waitcnt lgkmcnt(0)" ::: "memory");
    __builtin_amdgcn_sched_barrier(0);
    __builtin_amdgcn_s_setprio(1);
    MFMA_P(2);
    __builtin_amdgcn_s_setprio(0);
    __builtin_amdgcn_s_barrier();
  }

  if (z < 2) {
    unsigned short* out = z == 0 ? qb : kb;
#pragma unroll
    for (int mf = 0; mf < 4; ++mf)
#pragma unroll
      for (int nf = 0; nf < 4; ++nf) {
        int n = n0 + wc * 64 + nf * 16 + lr;
        int h = n >> 7, d = n & 127;
#pragma unroll
        for (int r = 0; r < 4; ++r) {
          int m = m0 + wr * 64 + mf * 16 + lg * 4 + r;
          int b = m >> 11, s = m & 2047;
          out[(((size_t)(b * NH + h)) * SEQ + s) * HD + d] = f2b(acc[mf][nf][r]);
        }
      }
  } else {
#pragma unroll
    for (int mf = 0; mf < 4; ++mf)
#pragma unroll
      for (int nf = 0; nf < 4; ++nf) {
        int dl = wc * 64 + nf * 16 + lr;
        int g = wr * 16 + mf * 4 + lg;
        int gs = g ^ ((dl & 7) << 2);
        u16x4 pk = {f2b(acc[mf][nf][0]), f2b(acc[mf][nf][1]),
                    f2b(acc[mf][nf][2]), f2b(acc[mf][nf][3])};
        *(u16x4*)&smem[dl * 128 + gs * 4] = pk;
      }
    __builtin_amdgcn_s_barrier();
    asm volatile("s_waitcnt lgkmcnt(0)" ::: "memory");
    int b = m0 >> 11, sbase = m0 & 2047;
#pragma unroll
    for (int p = 0; p < 8; ++p) {
      int f = p * 512 + tid;
      int dl = f >> 4, c8 = f & 15;
      int g0 = (2 * c8) ^ ((dl & 7) << 2);
      u16x8 v = *(const u16x8*)&smem[dl * 128 + g0 * 4];
      int n = n0 + dl;
      int h = n >> 7, d = n & 127;
      *(u16x8*)(vtb + (((size_t)(b * NH + h)) * HD + d) * SEQ + sbase + c8 * 8) = v;
    }
  }
}

// ---------------- kernel 4: causal flash attention ----------------
// 1024 blocks = 32 bh x 32 subtiles, LPT + XCD swizzle; 4 waves x 16 q-rows.
// K,V single-buffered LDS (32KB -> 4 blocks/CU); P redistributed in-register
// (cvt_pk + 16 ds_bpermute + selects, T12); defer-max (T13); setprio (T5).
__global__ __launch_bounds__(256, 4) void k_attn(
    const unsigned short* __restrict__ qb, const unsigned short* __restrict__ kb,
    const unsigned short* __restrict__ vtb, float* __restrict__ out) {
  __shared__ unsigned short Kl[64 * 128];   // [kv][d], chunk-XOR swizzled
  __shared__ unsigned short Vl[128 * 64];   // [d][kv], chunk-XOR swizzled

  const int id = blockIdx.x;
  const int swz = (id & 7) * 128 + (id >> 3);  // bijective over 1024
  const int bh = swz >> 5;                     // 4 consecutive bh per XCD
  const int qt = 31 - (swz & 31);              // heavy-first (LPT)
  const int q0 = qt * 64;
  const int b = bh >> 4, h = bh & 15;
  const int tid = threadIdx.x;
  const int wave = tid >> 6, lane = tid & 63;
  const int lr = lane & 15, lg = lane >> 4;
  const bool hi = lane >= 32;                  // lg >= 2

  const unsigned short* Qg = qb + (size_t)bh * SEQ * HD;
  const float C = 0.12751744155229827f;  // (1/sqrt(128)) * log2(e)

  // staging constants
  const int srow0 = tid >> 4;                 // K rows: p*16 + srow0
  const int ssc = (tid & 15) ^ (srow0 & 7);
  const int vrow = tid >> 3;                  // V rows: p*32 + vrow
  const int vsc = (tid & 7) ^ (vrow & 7);
  const unsigned short* Kt = kb + (size_t)bh * SEQ * HD;
  const unsigned short* Vst = vtb + (size_t)bh * HD * SEQ;

  // T12 gather lanes
  const int s0 = lr + 16 * ((2 * lg) & 3);
  const int s1 = lr + 16 * ((2 * lg + 1) & 3);

  bf16x8 qf[4];
#pragma unroll
  for (int ks = 0; ks < 4; ++ks)
    qf[ks] = *(const bf16x8*)&Qg[(size_t)(q0 + wave * 16 + lr) * HD + ks * 32 + lg * 8];

  f32x4 oacc[8] = {};
  float mraw = -1e30f;
  float lsum = 0.f;

  for (int t = 0; t <= qt; ++t) {
    // ---- stage K,V tile (single buffer) ----
#pragma unroll
    for (int p = 0; p < 4; ++p) {
      gl_lds16(Kt + (size_t)(p * 16 + srow0) * HD + ssc * 8, &Kl[p * 2048 + tid * 8]);
      gl_lds16(Vst + (size_t)(p * 32 + vrow) * SEQ + vsc * 8, &Vl[p * 2048 + tid * 8]);
    }
    Kt += 64 * HD;
    Vst += 64;
    asm volatile("s_waitcnt vmcnt(0)" ::: "memory");
    __syncthreads();

    // ---- QK^T (swapped): sacc[mf][r] = S[kv=16mf+4lg+r][q=lr] ----
    f32x4 sacc[4] = {};
    __builtin_amdgcn_s_setprio(1);
#pragma unroll
    for (int ks = 0; ks < 4; ++ks) {
      bf16x8 kf[4];
#pragma unroll
      for (int mf = 0; mf < 4; ++mf) {
        int row = mf * 16 + lr;
        kf[mf] = *(const bf16x8*)&Kl[row * 128 + ((lg + ks * 4) ^ (row & 7)) * 8];
      }
#pragma unroll
      for (int mf = 0; mf < 4; ++mf)
        sacc[mf] = __builtin_amdgcn_mfma_f32_16x16x32_bf16(kf[mf], qf[ks], sacc[mf], 0, 0, 0);
    }
    __builtin_amdgcn_s_setprio(0);

    if (t == qt) {  // diagonal: causal mask
      const int kv0 = t * 64;
#pragma unroll
      for (int mf = 0; mf < 4; ++mf)
#pragma unroll
        for (int r = 0; r < 4; ++r) {
          int kv = kv0 + mf * 16 + lg * 4 + r;
          int q = q0 + wave * 16 + lr;
          if (kv > q) sacc[mf][r] = -1e30f;
        }
    }

    // ---- row max (q = lr) ----
    float vm = fmaxf(fmaxf(fmaxf(sacc[0][0], sacc[0][1]), fmaxf(sacc[0][2], sacc[0][3])),
                     fmaxf(fmaxf(sacc[1][0], sacc[1][1]), fmaxf(sacc[1][2], sacc[1][3])));
    vm = fmaxf(vm,
               fmaxf(fmaxf(fmaxf(sacc[2][0], sacc[2][1]), fmaxf(sacc[2][2], sacc[2][3])),
                     fmaxf(fmaxf(sacc[3][0], sacc[3][1]), fmaxf(sacc[3][2], sacc[3][3]))));
    vm = fmaxf(vm, __shfl_xor(vm, 16));
    vm = fmaxf(vm, __shfl_xor(vm, 32));

    // ---- defer-max (T13) ----
    if (__any(vm - mraw > 60.0f)) {
      float nm = fmaxf(mraw, vm);
      float pfac = exp2f((mraw - nm) * C);
#pragma unroll
      for (int r = 0; r < 4; ++r) {
        float f = __shfl(pfac, lg * 4 + r);
#pragma unroll
        for (int nf8 = 0; nf8 < 8; ++nf8) oacc[nf8][r] *= f;
      }
      lsum *= pfac;
      mraw = nm;
    }
    const float mC = mraw * C;

    // ---- exp ----
#pragma unroll
    for (int mf = 0; mf < 4; ++mf)
#pragma unroll
      for (int r = 0; r < 4; ++r) sacc[mf][r] = exp2f(sacc[mf][r] * C - mC);

    // ---- row sum ----
    float ssum = 0.f;
#pragma unroll
    for (int mf = 0; mf < 4; ++mf)
#pragma unroll
      for (int r = 0; r < 4; ++r) ssum += sacc[mf][r];
    ssum += __shfl_xor(ssum, 16);
    ssum += __shfl_xor(ssum, 32);
    lsum += ssum;

    // ---- T12: pack P pairs + in-register redistribution to A-fragments ----
    unsigned pkv[4][2];
#pragma unroll
    for (int mf = 0; mf < 4; ++mf) {
      pkv[mf][0] = cvt_pk_bf16(sacc[mf][0], sacc[mf][1]);
      pkv[mf][1] = cvt_pk_bf16(sacc[mf][2], sacc[mf][3]);
    }
    unsigned q00a = __shfl((int)pkv[0][0], s0), q00b = __shfl((int)pkv[1][0], s0);
    unsigned q01a = __shfl((int)pkv[0][1], s0), q01b = __shfl((int)pkv[1][1], s0);
    unsigned q02a = __shfl((int)pkv[0][0], s1), q02b = __shfl((int)pkv[1][0], s1);
    unsigned q03a = __shfl((int)pkv[0][1], s1), q03b = __shfl((int)pkv[1][1], s1);
    u32x4 pw0 = {hi ? q00b : q00a, hi ? q01b : q01a, hi ? q02b : q02a, hi ? q03b : q03a};
    bf16x8 pf0 = __builtin_bit_cast(bf16x8, pw0);
    unsigned q10a = __shfl((int)pkv[2][0], s0), q10b = __shfl((int)pkv[3][0], s0);
    unsigned q11a = __shfl((int)pkv[2][1], s0), q11b = __shfl((int)pkv[3][1], s0);
    unsigned q12a = __shfl((int)pkv[2][0], s1), q12b = __shfl((int)pkv[3][0], s1);
    unsigned q13a = __shfl((int)pkv[2][1], s1), q13b = __shfl((int)pkv[3][1], s1);
    u32x4 pw1 = {hi ? q10b : q10a, hi ? q11b : q11a, hi ? q12b : q12a, hi ? q13b : q13a};
    bf16x8 pf1 = __builtin_bit_cast(bf16x8, pw1);

    // ---- O += P . V ----
    __builtin_amdgcn_s_setprio(1);
#pragma unroll
    for (int nf8 = 0; nf8 < 8; ++nf8) {
      int row = nf8 * 16 + lr;
      bf16x8 vf = *(const bf16x8*)&Vl[row * 64 + ((lg + 0 * 4) ^ (row & 7)) * 8];
      oacc[nf8] = __builtin_amdgcn_mfma_f32_16x16x32_bf16(pf0, vf, oacc[nf8], 0, 0, 0);
    }
#pragma unroll
    for (int nf8 = 0; nf8 < 8; ++nf8) {
      int row = nf8 * 16 + lr;
      bf16x8 vf = *(const bf16x8*)&Vl[row * 64 + ((lg + 1 * 4) ^ (row & 7)) * 8];
      oacc[nf8] = __builtin_amdgcn_mfma_f32_16x16x32_bf16(pf1, vf, oacc[nf8], 0, 0, 0);
    }
    __builtin_amdgcn_s_setprio(0);

    __syncthreads();
  }

  // ---- normalize + store fp32 ----
#pragma unroll
  for (int r = 0; r < 4; ++r) {
    float li = 1.0f / __shfl(lsum, lg * 4 + r);
    int q = q0 + wave * 16 + lg * 4 + r;
    float* orow = out + ((size_t)b * SEQ + q) * DM + h * HD;
#pragma unroll
    for (int nf8 = 0; nf8 < 8; ++nf8)
      orow[nf8 * 16 + lr] = oacc[nf8][r] * li;
  }
}

// ---------------- launcher ----------------
extern "C" void kernel_launch(void* const* d_in, const int* in_sizes, int n_in,
                              void* d_out, int out_size, void* d_ws, size_t ws_size,
                              hipStream_t stream) {
  const float* x  = (const float*)d_in[0];
  const float* Wq = (const float*)d_in[1];
  const float* Wk = (const float*)d_in[2];
  const float* Wv = (const float*)d_in[3];
  float* out = (float*)d_out;
  char* ws = (char*)d_ws;

  unsigned short* xb  = (unsigned short*)(ws);              // 4096x2048 bf16   (16 MB)
  unsigned short* wt  = (unsigned short*)(ws + 16777216);   // 3x 2048x2048 bf16 (24 MB)
  unsigned short* qb  = (unsigned short*)(ws + 41943040);   // [32][2048][128]  (16 MB)
  unsigned short* kb  = (unsigned short*)(ws + 58720256);   // [32][2048][128]  (16 MB)
  unsigned short* vtb = (unsigned short*)(ws + 75497472);   // [32][128][2048]  (16 MB)

  k_cvt_x<<<4096, 256, 0, stream>>>(x, xb);
  dim3 gw(32, 32, 3);
  k_cvt_w<<<gw, 256, 0, stream>>>(Wq, Wk, Wv, wt);
  k_qkv<<<768, 512, 0, stream>>>(xb, wt, qb, kb, vtb);
  k_attn<<<1024, 256, 0, stream>>>(qb, kb, vtb, out);
}

// Round 7
// 227.738 us; speedup vs baseline: 1.4001x; 1.0380x over previous
//
#include <hip/hip_runtime.h>

#define DM   2048
#define SEQ  2048
#define NB   2
#define NH   16
#define HD   128

typedef __bf16 bf16x8 __attribute__((ext_vector_type(8)));
typedef float f32x4 __attribute__((ext_vector_type(4)));
typedef unsigned short u16x4 __attribute__((ext_vector_type(4)));
typedef unsigned short u16x8 __attribute__((ext_vector_type(8)));
typedef unsigned int u32x4 __attribute__((ext_vector_type(4)));

__device__ __forceinline__ unsigned short f2b(float f) {
  return __builtin_bit_cast(unsigned short, (__bf16)f);
}

__device__ __forceinline__ unsigned cvt_pk_bf16(float lo, float hi) {
  unsigned r;
  asm("v_cvt_pk_bf16_f32 %0, %1, %2" : "=v"(r) : "v"(lo), "v"(hi));
  return r;
}

__device__ __forceinline__ void gl_lds16(const void* g, void* l) {
  __builtin_amdgcn_global_load_lds(
      (const __attribute__((address_space(1))) void*)g,
      (__attribute__((address_space(3))) void*)l, 16, 0, 0);
}

// ---------------- kernel 1: x fp32 -> bf16 ----------------
__global__ void k_cvt_x(const float* __restrict__ x, unsigned short* __restrict__ xb) {
  int i = blockIdx.x * 256 + threadIdx.x;
  const float4* src = (const float4*)x + (size_t)i * 2;
  float4 a = src[0], c = src[1];
  u16x8 o;
  o[0] = f2b(a.x); o[1] = f2b(a.y); o[2] = f2b(a.z); o[3] = f2b(a.w);
  o[4] = f2b(c.x); o[5] = f2b(c.y); o[6] = f2b(c.z); o[7] = f2b(c.w);
  *((u16x8*)xb + i) = o;
}

// ---------------- kernel 2: W fp32 [K][N] -> bf16 Wt [N][K] ----------------
__global__ void k_cvt_w(const float* __restrict__ Wq, const float* __restrict__ Wk,
                        const float* __restrict__ Wv, unsigned short* __restrict__ wts) {
  const float* W = blockIdx.z == 0 ? Wq : (blockIdx.z == 1 ? Wk : Wv);
  unsigned short* out = wts + (size_t)blockIdx.z * DM * DM;
  __shared__ unsigned short t[64 * 68];  // t[col][row]
  int c0 = blockIdx.x * 64, r0 = blockIdx.y * 64;
  int tr = threadIdx.x >> 4, tc = (threadIdx.x & 15) * 4;
#pragma unroll
  for (int p = 0; p < 4; ++p) {
    int r = p * 16 + tr;
    float4 v = *(const float4*)(W + (size_t)(r0 + r) * DM + c0 + tc);
    t[(tc + 0) * 68 + r] = f2b(v.x);
    t[(tc + 1) * 68 + r] = f2b(v.y);
    t[(tc + 2) * 68 + r] = f2b(v.z);
    t[(tc + 3) * 68 + r] = f2b(v.w);
  }
  __syncthreads();
#pragma unroll
  for (int p = 0; p < 4; ++p) {
    int c = p * 16 + tr;
    u16x4 o = *(const u16x4*)&t[c * 68 + tc];
    *(u16x4*)(out + (size_t)(c0 + c) * DM + r0 + tc) = o;
  }
}

// ---------------- kernel 3: QKV GEMM, 128x256 tile, 2-phase 8-wave ----------------
#define NT_ 32

#define ST_A(T)                                                                \
  if ((T) < NT_) {                                                             \
    const int ktS = (T);                                                       \
    const unsigned ab_ = (ktS & 1) * 8192u;                                    \
    gl_lds16(Ag + (size_t)srow * DM + ktS * 64 + sgcol, &smem[ab_ + bo0]);     \
    gl_lds16(Ag + (size_t)(64 + srow) * DM + ktS * 64 + sgcol,                 \
             &smem[ab_ + 4096 + bo0]);                                         \
  }

#define ST_B1(T)                                                               \
  if ((T) < NT_) {                                                             \
    const int ktS = (T);                                                       \
    const unsigned bb_ = 16384u + (ktS & 1) * 16384u;                          \
    gl_lds16(Bg + (size_t)grB * DM + ktS * 64 + sgcol, &smem[bb_ + bo1]);      \
    gl_lds16(Bg + (size_t)(grB + 128) * DM + ktS * 64 + sgcol,                 \
             &smem[bb_ + 8192 + bo1]);                                         \
  }

#define ST_B2(T)                                                               \
  if ((T) < NT_) {                                                             \
    const int ktS = (T);                                                       \
    const unsigned bb_ = 16384u + (ktS & 1) * 16384u;                          \
    gl_lds16(Bg + (size_t)(grB + 32) * DM + ktS * 64 + sgcol,                  \
             &smem[bb_ + 2048 + bo1]);                                         \
    gl_lds16(Bg + (size_t)(grB + 160) * DM + ktS * 64 + sgcol,                 \
             &smem[bb_ + 10240 + bo1]);                                        \
  }

#define DS_A_ALL                                                               \
  {                                                                            \
    _Pragma("unroll") for (int mf_ = 0; mf_ < 4; ++mf_) {                      \
      int row_ = wr * 64 + mf_ * 16 + lr;                                      \
      _Pragma("unroll") for (int ks_ = 0; ks_ < 2; ++ks_)                      \
        af[mf_][ks_] = *(const bf16x8*)&smem[ab + row_ * 64 +                  \
                                             (((lg + ks_ * 4) ^ (lr & 7)) * 8)];\
    }                                                                          \
  }

#define DS_B(NF, J)                                                            \
  {                                                                            \
    int row_ = wc * 64 + (NF)*16 + lr;                                         \
    _Pragma("unroll") for (int ks_ = 0; ks_ < 2; ++ks_)                        \
      bfr[J][ks_] = *(const bf16x8*)&smem[bb + row_ * 64 +                     \
                                          (((lg + ks_ * 4) ^ (lr & 7)) * 8)];  \
  }

#define MFMA_P(NFB)                                                            \
  {                                                                            \
    _Pragma("unroll") for (int mf_ = 0; mf_ < 4; ++mf_)                        \
    _Pragma("unroll") for (int j_ = 0; j_ < 2; ++j_)                           \
    _Pragma("unroll") for (int ks_ = 0; ks_ < 2; ++ks_)                        \
      acc[mf_][(NFB) + j_] = __builtin_amdgcn_mfma_f32_16x16x32_bf16(          \
          af[mf_][ks_], bfr[j_][ks_], acc[mf_][(NFB) + j_], 0, 0, 0);          \
  }

__global__ __launch_bounds__(512, 2) void k_qkv(
    const unsigned short* __restrict__ xb, const unsigned short* __restrict__ wts,
    unsigned short* __restrict__ qb, unsigned short* __restrict__ kb,
    unsigned short* __restrict__ vtb) {
  __shared__ unsigned short smem[49152];

  const int id = blockIdx.x;
  const int swz = (id & 7) * 96 + (id >> 3);
  const int z = swz >> 8;
  const int rem = swz & 255;
  const int m0 = (rem >> 3) * 128;
  const int n0 = (rem & 7) * 256;

  const unsigned short* Ag = xb + (size_t)m0 * DM;
  const unsigned short* Bg = wts + (size_t)z * DM * DM + (size_t)n0 * DM;

  const int tid = threadIdx.x;
  const int wave = tid >> 6, lane = tid & 63;
  const int lr = lane & 15, lg = lane >> 4;
  const int wr = wave >> 2, wc = wave & 3;
  const int srow = tid >> 3;
  const int sgcol = ((tid & 7) ^ (srow & 7)) * 8;
  const int grB = srow + (srow & 32);
  const unsigned bo0 = wave * 512u;
  const unsigned bo1 = wave * 512u + ((wave & 4) << 9);

  f32x4 acc[4][4] = {};
  bf16x8 af[4][2], bfr[2][2];

  ST_A(0); ST_B1(0); ST_B2(0); ST_A(1); ST_B1(1);
  asm volatile("s_waitcnt vmcnt(4)" ::: "memory");
  __builtin_amdgcn_s_barrier();

  for (int t = 0; t < NT_; ++t) {
    const unsigned ab = (t & 1) * 8192u;
    const unsigned bb = 16384u + (t & 1) * 16384u;

    DS_A_ALL;
    DS_B(0, 0); DS_B(1, 1);
    ST_B2(t + 1);
    asm volatile("s_waitcnt lgkmcnt(8)" ::: "memory");
    __builtin_amdgcn_s_barrier();
    asm volatile("s_waitcnt lgkmcnt(0)" ::: "memory");
    __builtin_amdgcn_sched_barrier(0);
    __builtin_amdgcn_s_setprio(1);
    MFMA_P(0);
    __builtin_amdgcn_s_setprio(0);
    __builtin_amdgcn_s_barrier();

    DS_B(2, 0); DS_B(3, 1);
    ST_A(t + 2); ST_B1(t + 2);
    if (t < NT_ - 2)
      asm volatile("s_waitcnt vmcnt(4)" ::: "memory");
    else
      asm volatile("s_waitcnt vmcnt(0)" ::: "memory");
    __builtin_amdgcn_s_barrier();
    asm volatile("s_waitcnt lgkmcnt(0)" ::: "memory");
    __builtin_amdgcn_sched_barrier(0);
    __builtin_amdgcn_s_setprio(1);
    MFMA_P(2);
    __builtin_amdgcn_s_setprio(0);
    __builtin_amdgcn_s_barrier();
  }

  if (z < 2) {
    unsigned short* out = z == 0 ? qb : kb;
#pragma unroll
    for (int mf = 0; mf < 4; ++mf)
#pragma unroll
      for (int nf = 0; nf < 4; ++nf) {
        int n = n0 + wc * 64 + nf * 16 + lr;
        int h = n >> 7, d = n & 127;
#pragma unroll
        for (int r = 0; r < 4; ++r) {
          int m = m0 + wr * 64 + mf * 16 + lg * 4 + r;
          int b = m >> 11, s = m & 2047;
          out[(((size_t)(b * NH + h)) * SEQ + s) * HD + d] = f2b(acc[mf][nf][r]);
        }
      }
  } else {
#pragma unroll
    for (int mf = 0; mf < 4; ++mf)
#pragma unroll
      for (int nf = 0; nf < 4; ++nf) {
        int dl = wc * 64 + nf * 16 + lr;
        int g = wr * 16 + mf * 4 + lg;
        int gs = g ^ ((dl & 7) << 2);
        u16x4 pk = {f2b(acc[mf][nf][0]), f2b(acc[mf][nf][1]),
                    f2b(acc[mf][nf][2]), f2b(acc[mf][nf][3])};
        *(u16x4*)&smem[dl * 128 + gs * 4] = pk;
      }
    __builtin_amdgcn_s_barrier();
    asm volatile("s_waitcnt lgkmcnt(0)" ::: "memory");
    int b = m0 >> 11, sbase = m0 & 2047;
#pragma unroll
    for (int p = 0; p < 8; ++p) {
      int f = p * 512 + tid;
      int dl = f >> 4, c8 = f & 15;
      int g0 = (2 * c8) ^ ((dl & 7) << 2);
      u16x8 v = *(const u16x8*)&smem[dl * 128 + g0 * 4];
      int n = n0 + dl;
      int h = n >> 7, d = n & 127;
      *(u16x8*)(vtb + (((size_t)(b * NH + h)) * HD + d) * SEQ + sbase + c8 * 8) = v;
    }
  }
}

// ---------------- kernel 4: causal flash attention, nf=2 amortized ----------------
// 512 blocks = 32 bh x 16 subtiles (128 q-rows), LPT + XCD swizzle.
// 4 waves x 32 q-rows (2 fragments/wave). K,V single-buffered LDS (32KB).
// In-register P redistribution (T12), defer-max (T13), setprio (T5).
__global__ __launch_bounds__(256, 2) void k_attn(
    const unsigned short* __restrict__ qb, const unsigned short* __restrict__ kb,
    const unsigned short* __restrict__ vtb, float* __restrict__ out) {
  __shared__ unsigned short Kl[64 * 128];   // [kv][d], chunk-XOR swizzled
  __shared__ unsigned short Vl[128 * 64];   // [d][kv], chunk-XOR swizzled

  const int id = blockIdx.x;
  const int swz = (id & 7) * 64 + (id >> 3);   // bijective over 512
  const int bh = swz >> 4;                     // 4 consecutive bh per XCD
  const int qt = 15 - (swz & 15);              // heavy-first (LPT)
  const int q0 = qt * 128;
  const int b = bh >> 4, h = bh & 15;
  const int tid = threadIdx.x;
  const int wave = tid >> 6, lane = tid & 63;
  const int lr = lane & 15, lg = lane >> 4;
  const bool hi = lane >= 32;

  const unsigned short* Qg = qb + (size_t)bh * SEQ * HD;
  const float C = 0.12751744155229827f;  // (1/sqrt(128)) * log2(e)

  // staging constants
  const int srow0 = tid >> 4;                 // K rows: p*16 + srow0
  const int ssc = (tid & 15) ^ (srow0 & 7);
  const int vrow = tid >> 3;                  // V rows: p*32 + vrow
  const int vsc = (tid & 7) ^ (vrow & 7);
  const unsigned short* Kt = kb + (size_t)bh * SEQ * HD;
  const unsigned short* Vst = vtb + (size_t)bh * HD * SEQ;

  // T12 gather lanes
  const int s0 = lr + 16 * ((2 * lg) & 3);
  const int s1 = lr + 16 * ((2 * lg + 1) & 3);

  bf16x8 qf0[4], qf1[4];
#pragma unroll
  for (int ks = 0; ks < 4; ++ks) {
    qf0[ks] = *(const bf16x8*)&Qg[(size_t)(q0 + wave * 32 + lr) * HD + ks * 32 + lg * 8];
    qf1[ks] = *(const bf16x8*)&Qg[(size_t)(q0 + wave * 32 + 16 + lr) * HD + ks * 32 + lg * 8];
  }

  f32x4 oacc0[8] = {}, oacc1[8] = {};
  float mraw0 = -1e30f, mraw1 = -1e30f;
  float lsum0 = 0.f, lsum1 = 0.f;

  const int ntiles = 2 * qt + 2;
  for (int t = 0; t < ntiles; ++t) {
    // ---- stage K,V tile (single buffer) ----
#pragma unroll
    for (int p = 0; p < 4; ++p) {
      gl_lds16(Kt + (size_t)(p * 16 + srow0) * HD + ssc * 8, &Kl[p * 2048 + tid * 8]);
      gl_lds16(Vst + (size_t)(p * 32 + vrow) * SEQ + vsc * 8, &Vl[p * 2048 + tid * 8]);
    }
    Kt += 64 * HD;
    Vst += 64;
    asm volatile("s_waitcnt vmcnt(0)" ::: "memory");
    __syncthreads();

    // ---- QK^T (swapped), both fragments share kf reads ----
    f32x4 sacc0[4] = {}, sacc1[4] = {};
    __builtin_amdgcn_s_setprio(1);
#pragma unroll
    for (int ks = 0; ks < 4; ++ks) {
      bf16x8 kf[4];
#pragma unroll
      for (int mf = 0; mf < 4; ++mf) {
        int row = mf * 16 + lr;
        kf[mf] = *(const bf16x8*)&Kl[row * 128 + ((lg + ks * 4) ^ (row & 7)) * 8];
      }
#pragma unroll
      for (int mf = 0; mf < 4; ++mf) {
        sacc0[mf] = __builtin_amdgcn_mfma_f32_16x16x32_bf16(kf[mf], qf0[ks], sacc0[mf], 0, 0, 0);
        sacc1[mf] = __builtin_amdgcn_mfma_f32_16x16x32_bf16(kf[mf], qf1[ks], sacc1[mf], 0, 0, 0);
      }
    }
    __builtin_amdgcn_s_setprio(0);

    if (t >= 2 * qt) {  // diagonal region: causal mask
      const int kv0 = t * 64;
#pragma unroll
      for (int mf = 0; mf < 4; ++mf)
#pragma unroll
        for (int r = 0; r < 4; ++r) {
          int kv = kv0 + mf * 16 + lg * 4 + r;
          int qA = q0 + wave * 32 + lr;
          int qB = qA + 16;
          if (kv > qA) sacc0[mf][r] = -1e30f;
          if (kv > qB) sacc1[mf][r] = -1e30f;
        }
    }

    // ---- row max per fragment (ILP) ----
    float vm0 = fmaxf(fmaxf(fmaxf(sacc0[0][0], sacc0[0][1]), fmaxf(sacc0[0][2], sacc0[0][3])),
                      fmaxf(fmaxf(sacc0[1][0], sacc0[1][1]), fmaxf(sacc0[1][2], sacc0[1][3])));
    vm0 = fmaxf(vm0,
                fmaxf(fmaxf(fmaxf(sacc0[2][0], sacc0[2][1]), fmaxf(sacc0[2][2], sacc0[2][3])),
                      fmaxf(fmaxf(sacc0[3][0], sacc0[3][1]), fmaxf(sacc0[3][2], sacc0[3][3]))));
    float vm1 = fmaxf(fmaxf(fmaxf(sacc1[0][0], sacc1[0][1]), fmaxf(sacc1[0][2], sacc1[0][3])),
                      fmaxf(fmaxf(sacc1[1][0], sacc1[1][1]), fmaxf(sacc1[1][2], sacc1[1][3])));
    vm1 = fmaxf(vm1,
                fmaxf(fmaxf(fmaxf(sacc1[2][0], sacc1[2][1]), fmaxf(sacc1[2][2], sacc1[2][3])),
                      fmaxf(fmaxf(sacc1[3][0], sacc1[3][1]), fmaxf(sacc1[3][2], sacc1[3][3]))));
    vm0 = fmaxf(vm0, __shfl_xor(vm0, 16));
    vm1 = fmaxf(vm1, __shfl_xor(vm1, 16));
    vm0 = fmaxf(vm0, __shfl_xor(vm0, 32));
    vm1 = fmaxf(vm1, __shfl_xor(vm1, 32));

    // ---- defer-max (T13), combined vote ----
    if (__any(fmaxf(vm0 - mraw0, vm1 - mraw1) > 60.0f)) {
      float nm0 = fmaxf(mraw0, vm0), nm1 = fmaxf(mraw1, vm1);
      float pf0 = exp2f((mraw0 - nm0) * C), pf1 = exp2f((mraw1 - nm1) * C);
#pragma unroll
      for (int r = 0; r < 4; ++r) {
        float f0 = __shfl(pf0, lg * 4 + r);
        float f1 = __shfl(pf1, lg * 4 + r);
#pragma unroll
        for (int nf8 = 0; nf8 < 8; ++nf8) {
          oacc0[nf8][r] *= f0;
          oacc1[nf8][r] *= f1;
        }
      }
      lsum0 *= pf0; lsum1 *= pf1;
      mraw0 = nm0; mraw1 = nm1;
    }
    const float mC0 = mraw0 * C, mC1 = mraw1 * C;

    // ---- exp ----
#pragma unroll
    for (int mf = 0; mf < 4; ++mf)
#pragma unroll
      for (int r = 0; r < 4; ++r) {
        sacc0[mf][r] = exp2f(sacc0[mf][r] * C - mC0);
        sacc1[mf][r] = exp2f(sacc1[mf][r] * C - mC1);
      }

    // ---- row sum ----
    float ss0 = 0.f, ss1 = 0.f;
#pragma unroll
    for (int mf = 0; mf < 4; ++mf)
#pragma unroll
      for (int r = 0; r < 4; ++r) { ss0 += sacc0[mf][r]; ss1 += sacc1[mf][r]; }
    ss0 += __shfl_xor(ss0, 16);
    ss1 += __shfl_xor(ss1, 16);
    ss0 += __shfl_xor(ss0, 32);
    ss1 += __shfl_xor(ss1, 32);
    lsum0 += ss0; lsum1 += ss1;

    // ---- T12: pack + in-register redistribution, per fragment ----
    bf16x8 pA0, pA1, pB0, pB1;  // frag0 halves, frag1 halves
    {
      unsigned pk0[4][2], pk1[4][2];
#pragma unroll
      for (int mf = 0; mf < 4; ++mf) {
        pk0[mf][0] = cvt_pk_bf16(sacc0[mf][0], sacc0[mf][1]);
        pk0[mf][1] = cvt_pk_bf16(sacc0[mf][2], sacc0[mf][3]);
        pk1[mf][0] = cvt_pk_bf16(sacc1[mf][0], sacc1[mf][1]);
        pk1[mf][1] = cvt_pk_bf16(sacc1[mf][2], sacc1[mf][3]);
      }
#define REDIST(PKV, LOW, HIGH)                                                 \
      {                                                                        \
        unsigned a0 = __shfl((int)PKV[0 + (LOW)][0], s0),                      \
                 b0 = __shfl((int)PKV[1 + (LOW)][0], s0);                      \
        unsigned a1 = __shfl((int)PKV[0 + (LOW)][1], s0),                      \
                 b1 = __shfl((int)PKV[1 + (LOW)][1], s0);                      \
        unsigned a2 = __shfl((int)PKV[0 + (LOW)][0], s1),                      \
                 b2 = __shfl((int)PKV[1 + (LOW)][0], s1);                      \
        unsigned a3 = __shfl((int)PKV[0 + (LOW)][1], s1),                      \
                 b3 = __shfl((int)PKV[1 + (LOW)][1], s1);                      \
        u32x4 w = {hi ? b0 : a0, hi ? b1 : a1, hi ? b2 : a2, hi ? b3 : a3};    \
        HIGH = __builtin_bit_cast(bf16x8, w);                                  \
      }
      REDIST(pk0, 0, pA0);
      REDIST(pk0, 2, pB0);
      REDIST(pk1, 0, pA1);
      REDIST(pk1, 2, pB1);
#undef REDIST
    }

    // ---- O += P . V (vf shared across fragments) ----
    __builtin_amdgcn_s_setprio(1);
#pragma unroll
    for (int nf8 = 0; nf8 < 8; ++nf8) {
      int row = nf8 * 16 + lr;
      bf16x8 vf = *(const bf16x8*)&Vl[row * 64 + (lg ^ (row & 7)) * 8];
      oacc0[nf8] = __builtin_amdgcn_mfma_f32_16x16x32_bf16(pA0, vf, oacc0[nf8], 0, 0, 0);
      oacc1[nf8] = __builtin_amdgcn_mfma_f32_16x16x32_bf16(pA1, vf, oacc1[nf8], 0, 0, 0);
    }
#pragma unroll
    for (int nf8 = 0; nf8 < 8; ++nf8) {
      int row = nf8 * 16 + lr;
      bf16x8 vf = *(const bf16x8*)&Vl[row * 64 + ((lg + 4) ^ (row & 7)) * 8];
      oacc0[nf8] = __builtin_amdgcn_mfma_f32_16x16x32_bf16(pB0, vf, oacc0[nf8], 0, 0, 0);
      oacc1[nf8] = __builtin_amdgcn_mfma_f32_16x16x32_bf16(pB1, vf, oacc1[nf8], 0, 0, 0);
    }
    __builtin_amdgcn_s_setprio(0);

    __syncthreads();
  }

  // ---- normalize + store fp32, both fragments ----
#pragma unroll
  for (int r = 0; r < 4; ++r) {
    float li0 = 1.0f / __shfl(lsum0, lg * 4 + r);
    float li1 = 1.0f / __shfl(lsum1, lg * 4 + r);
    int qA = q0 + wave * 32 + lg * 4 + r;
    float* orowA = out + ((size_t)b * SEQ + qA) * DM + h * HD;
    float* orowB = orowA + (size_t)16 * DM;
#pragma unroll
    for (int nf8 = 0; nf8 < 8; ++nf8) {
      orowA[nf8 * 16 + lr] = oacc0[nf8][r] * li0;
      orowB[nf8 * 16 + lr] = oacc1[nf8][r] * li1;
    }
  }
}

// ---------------- launcher ----------------
extern "C" void kernel_launch(void* const* d_in, const int* in_sizes, int n_in,
                              void* d_out, int out_size, void* d_ws, size_t ws_size,
                              hipStream_t stream) {
  const float* x  = (const float*)d_in[0];
  const float* Wq = (const float*)d_in[1];
  const float* Wk = (const float*)d_in[2];
  const float* Wv = (const float*)d_in[3];
  float* out = (float*)d_out;
  char* ws = (char*)d_ws;

  unsigned short* xb  = (unsigned short*)(ws);              // 4096x2048 bf16   (16 MB)
  unsigned short* wt  = (unsigned short*)(ws + 16777216);   // 3x 2048x2048 bf16 (24 MB)
  unsigned short* qb  = (unsigned short*)(ws + 41943040);   // [32][2048][128]  (16 MB)
  unsigned short* kb  = (unsigned short*)(ws + 58720256);   // [32][2048][128]  (16 MB)
  unsigned short* vtb = (unsigned short*)(ws + 75497472);   // [32][128][2048]  (16 MB)

  k_cvt_x<<<4096, 256, 0, stream>>>(x, xb);
  dim3 gw(32, 32, 3);
  k_cvt_w<<<gw, 256, 0, stream>>>(Wq, Wk, Wv, wt);
  k_qkv<<<768, 512, 0, stream>>>(xb, wt, qb, kb, vtb);
  k_attn<<<512, 256, 0, stream>>>(qb, kb, vtb, out);
}

// Round 8
// 216.695 us; speedup vs baseline: 1.4714x; 1.0510x over previous
//
#include <hip/hip_runtime.h>

#define DM   2048
#define SEQ  2048
#define NB   2
#define NH   16
#define HD   128

typedef __bf16 bf16x8 __attribute__((ext_vector_type(8)));
typedef float f32x4 __attribute__((ext_vector_type(4)));
typedef unsigned short u16x4 __attribute__((ext_vector_type(4)));
typedef unsigned short u16x8 __attribute__((ext_vector_type(8)));
typedef unsigned int u32x4 __attribute__((ext_vector_type(4)));

__device__ __forceinline__ unsigned short f2b(float f) {
  return __builtin_bit_cast(unsigned short, (__bf16)f);
}

__device__ __forceinline__ unsigned cvt_pk_bf16(float lo, float hi) {
  unsigned r;
  asm("v_cvt_pk_bf16_f32 %0, %1, %2" : "=v"(r) : "v"(lo), "v"(hi));
  return r;
}

__device__ __forceinline__ void gl_lds16(const void* g, void* l) {
  __builtin_amdgcn_global_load_lds(
      (const __attribute__((address_space(1))) void*)g,
      (__attribute__((address_space(3))) void*)l, 16, 0, 0);
}

// ---------------- kernel 1: x fp32 -> bf16 ----------------
__global__ void k_cvt_x(const float* __restrict__ x, unsigned short* __restrict__ xb) {
  int i = blockIdx.x * 256 + threadIdx.x;
  const float4* src = (const float4*)x + (size_t)i * 2;
  float4 a = src[0], c = src[1];
  u16x8 o;
  o[0] = f2b(a.x); o[1] = f2b(a.y); o[2] = f2b(a.z); o[3] = f2b(a.w);
  o[4] = f2b(c.x); o[5] = f2b(c.y); o[6] = f2b(c.z); o[7] = f2b(c.w);
  *((u16x8*)xb + i) = o;
}

// ---------------- kernel 2: W fp32 [K][N] -> bf16 Wt [N][K] ----------------
__global__ void k_cvt_w(const float* __restrict__ Wq, const float* __restrict__ Wk,
                        const float* __restrict__ Wv, unsigned short* __restrict__ wts) {
  const float* W = blockIdx.z == 0 ? Wq : (blockIdx.z == 1 ? Wk : Wv);
  unsigned short* out = wts + (size_t)blockIdx.z * DM * DM;
  __shared__ unsigned short t[64 * 68];  // t[col][row]
  int c0 = blockIdx.x * 64, r0 = blockIdx.y * 64;
  int tr = threadIdx.x >> 4, tc = (threadIdx.x & 15) * 4;
#pragma unroll
  for (int p = 0; p < 4; ++p) {
    int r = p * 16 + tr;
    float4 v = *(const float4*)(W + (size_t)(r0 + r) * DM + c0 + tc);
    t[(tc + 0) * 68 + r] = f2b(v.x);
    t[(tc + 1) * 68 + r] = f2b(v.y);
    t[(tc + 2) * 68 + r] = f2b(v.z);
    t[(tc + 3) * 68 + r] = f2b(v.w);
  }
  __syncthreads();
#pragma unroll
  for (int p = 0; p < 4; ++p) {
    int c = p * 16 + tr;
    u16x4 o = *(const u16x4*)&t[c * 68 + tc];
    *(u16x4*)(out + (size_t)(c0 + c) * DM + r0 + tc) = o;
  }
}

// ---------------- kernel 3: QKV GEMM, 128x256 tile, 2-phase 8-wave ----------------
#define NT_ 32

#define ST_A(T)                                                                \
  if ((T) < NT_) {                                                             \
    const int ktS = (T);                                                       \
    const unsigned ab_ = (ktS & 1) * 8192u;                                    \
    gl_lds16(Ag + (size_t)srow * DM + ktS * 64 + sgcol, &smem[ab_ + bo0]);     \
    gl_lds16(Ag + (size_t)(64 + srow) * DM + ktS * 64 + sgcol,                 \
             &smem[ab_ + 4096 + bo0]);                                         \
  }

#define ST_B1(T)                                                               \
  if ((T) < NT_) {                                                             \
    const int ktS = (T);                                                       \
    const unsigned bb_ = 16384u + (ktS & 1) * 16384u;                          \
    gl_lds16(Bg + (size_t)grB * DM + ktS * 64 + sgcol, &smem[bb_ + bo1]);      \
    gl_lds16(Bg + (size_t)(grB + 128) * DM + ktS * 64 + sgcol,                 \
             &smem[bb_ + 8192 + bo1]);                                         \
  }

#define ST_B2(T)                                                               \
  if ((T) < NT_) {                                                             \
    const int ktS = (T);                                                       \
    const unsigned bb_ = 16384u + (ktS & 1) * 16384u;                          \
    gl_lds16(Bg + (size_t)(grB + 32) * DM + ktS * 64 + sgcol,                  \
             &smem[bb_ + 2048 + bo1]);                                         \
    gl_lds16(Bg + (size_t)(grB + 160) * DM + ktS * 64 + sgcol,                 \
             &smem[bb_ + 10240 + bo1]);                                        \
  }

#define DS_A_ALL                                                               \
  {                                                                            \
    _Pragma("unroll") for (int mf_ = 0; mf_ < 4; ++mf_) {                      \
      int row_ = wr * 64 + mf_ * 16 + lr;                                      \
      _Pragma("unroll") for (int ks_ = 0; ks_ < 2; ++ks_)                      \
        af[mf_][ks_] = *(const bf16x8*)&smem[ab + row_ * 64 +                  \
                                             (((lg + ks_ * 4) ^ (lr & 7)) * 8)];\
    }                                                                          \
  }

#define DS_B(NF, J)                                                            \
  {                                                                            \
    int row_ = wc * 64 + (NF)*16 + lr;                                         \
    _Pragma("unroll") for (int ks_ = 0; ks_ < 2; ++ks_)                        \
      bfr[J][ks_] = *(const bf16x8*)&smem[bb + row_ * 64 +                     \
                                          (((lg + ks_ * 4) ^ (lr & 7)) * 8)];  \
  }

#define MFMA_P(NFB)                                                            \
  {                                                                            \
    _Pragma("unroll") for (int mf_ = 0; mf_ < 4; ++mf_)                        \
    _Pragma("unroll") for (int j_ = 0; j_ < 2; ++j_)                           \
    _Pragma("unroll") for (int ks_ = 0; ks_ < 2; ++ks_)                        \
      acc[mf_][(NFB) + j_] = __builtin_amdgcn_mfma_f32_16x16x32_bf16(          \
          af[mf_][ks_], bfr[j_][ks_], acc[mf_][(NFB) + j_], 0, 0, 0);          \
  }

__global__ __launch_bounds__(512, 2) void k_qkv(
    const unsigned short* __restrict__ xb, const unsigned short* __restrict__ wts,
    unsigned short* __restrict__ qb, unsigned short* __restrict__ kb,
    unsigned short* __restrict__ vtb) {
  __shared__ unsigned short smem[49152];

  const int id = blockIdx.x;
  const int swz = (id & 7) * 96 + (id >> 3);
  const int z = swz >> 8;
  const int rem = swz & 255;
  const int m0 = (rem >> 3) * 128;
  const int n0 = (rem & 7) * 256;

  const unsigned short* Ag = xb + (size_t)m0 * DM;
  const unsigned short* Bg = wts + (size_t)z * DM * DM + (size_t)n0 * DM;

  const int tid = threadIdx.x;
  const int wave = tid >> 6, lane = tid & 63;
  const int lr = lane & 15, lg = lane >> 4;
  const int wr = wave >> 2, wc = wave & 3;
  const int srow = tid >> 3;
  const int sgcol = ((tid & 7) ^ (srow & 7)) * 8;
  const int grB = srow + (srow & 32);
  const unsigned bo0 = wave * 512u;
  const unsigned bo1 = wave * 512u + ((wave & 4) << 9);

  f32x4 acc[4][4] = {};
  bf16x8 af[4][2], bfr[2][2];

  ST_A(0); ST_B1(0); ST_B2(0); ST_A(1); ST_B1(1);
  asm volatile("s_waitcnt vmcnt(4)" ::: "memory");
  __builtin_amdgcn_s_barrier();

  for (int t = 0; t < NT_; ++t) {
    const unsigned ab = (t & 1) * 8192u;
    const unsigned bb = 16384u + (t & 1) * 16384u;

    DS_A_ALL;
    DS_B(0, 0); DS_B(1, 1);
    ST_B2(t + 1);
    asm volatile("s_waitcnt lgkmcnt(8)" ::: "memory");
    __builtin_amdgcn_s_barrier();
    asm volatile("s_waitcnt lgkmcnt(0)" ::: "memory");
    __builtin_amdgcn_sched_barrier(0);
    __builtin_amdgcn_s_setprio(1);
    MFMA_P(0);
    __builtin_amdgcn_s_setprio(0);
    __builtin_amdgcn_s_barrier();

    DS_B(2, 0); DS_B(3, 1);
    ST_A(t + 2); ST_B1(t + 2);
    if (t < NT_ - 2)
      asm volatile("s_waitcnt vmcnt(4)" ::: "memory");
    else
      asm volatile("s_waitcnt vmcnt(0)" ::: "memory");
    __builtin_amdgcn_s_barrier();
    asm volatile("s_waitcnt lgkmcnt(0)" ::: "memory");
    __builtin_amdgcn_sched_barrier(0);
    __builtin_amdgcn_s_setprio(1);
    MFMA_P(2);
    __builtin_amdgcn_s_setprio(0);
    __builtin_amdgcn_s_barrier();
  }

  if (z < 2) {
    unsigned short* out = z == 0 ? qb : kb;
#pragma unroll
    for (int mf = 0; mf < 4; ++mf)
#pragma unroll
      for (int nf = 0; nf < 4; ++nf) {
        int n = n0 + wc * 64 + nf * 16 + lr;
        int h = n >> 7, d = n & 127;
#pragma unroll
        for (int r = 0; r < 4; ++r) {
          int m = m0 + wr * 64 + mf * 16 + lg * 4 + r;
          int b = m >> 11, s = m & 2047;
          out[(((size_t)(b * NH + h)) * SEQ + s) * HD + d] = f2b(acc[mf][nf][r]);
        }
      }
  } else {
#pragma unroll
    for (int mf = 0; mf < 4; ++mf)
#pragma unroll
      for (int nf = 0; nf < 4; ++nf) {
        int dl = wc * 64 + nf * 16 + lr;
        int g = wr * 16 + mf * 4 + lg;
        int gs = g ^ ((dl & 7) << 2);
        u16x4 pk = {f2b(acc[mf][nf][0]), f2b(acc[mf][nf][1]),
                    f2b(acc[mf][nf][2]), f2b(acc[mf][nf][3])};
        *(u16x4*)&smem[dl * 128 + gs * 4] = pk;
      }
    __builtin_amdgcn_s_barrier();
    asm volatile("s_waitcnt lgkmcnt(0)" ::: "memory");
    int b = m0 >> 11, sbase = m0 & 2047;
#pragma unroll
    for (int p = 0; p < 8; ++p) {
      int f = p * 512 + tid;
      int dl = f >> 4, c8 = f & 15;
      int g0 = (2 * c8) ^ ((dl & 7) << 2);
      u16x8 v = *(const u16x8*)&smem[dl * 128 + g0 * 4];
      int n = n0 + dl;
      int h = n >> 7, d = n & 127;
      *(u16x8*)(vtb + (((size_t)(b * NH + h)) * HD + d) * SEQ + sbase + c8 * 8) = v;
    }
  }
}

// ---------------- kernel 4: causal flash attention, balanced KVBLK=128 ----------------
// 256 blocks x 4 waves; block = pair of 128-row subtiles (x, 15-x) -> uniform 17 KV-tiles.
// K/V double-buffered (128 KB LDS), counted vmcnt(16) prefetch; nf=2 per wave;
// in-register P redistribution (T12); defer-max (T13). 4 bh per XCD (L2-fit).
__global__ __launch_bounds__(256, 1) void k_attn(
    const unsigned short* __restrict__ qb, const unsigned short* __restrict__ kb,
    const unsigned short* __restrict__ vtb, float* __restrict__ out) {
  __shared__ unsigned short Kl[2][128 * 128];   // [kv][d], chunk-XOR swizzled (32KB x2)
  __shared__ unsigned short Vl[2][128 * 128];   // [d][kv], chunk-XOR swizzled (32KB x2)

  const int id = blockIdx.x;
  const int bh = 4 * (id & 7) + (id >> 6);        // 4 bh per XCD
  const int px = (id >> 3) & 7;                   // pair index 0..7
  const int b = bh >> 4, h = bh & 15;
  const int tid = threadIdx.x;
  const int wave = tid >> 6, lane = tid & 63;
  const int lr = lane & 15, lg = lane >> 4;
  const bool hi = lane >= 32;

  const unsigned short* Qg = qb + (size_t)bh * SEQ * HD;
  const unsigned short* Kg = kb + (size_t)bh * SEQ * HD;
  const unsigned short* Vg = vtb + (size_t)bh * HD * SEQ;
  const float C = 0.12751744155229827f;  // (1/sqrt(128)) * log2(e)

  const int srow0 = tid >> 4;                      // 0..15
  const int ssc = ((tid & 15) ^ (srow0 & 7)) * 8;  // pre-swizzled source chunk

  // T12 gather lanes
  const int s0 = lr + 16 * ((2 * lg) & 3);
  const int s1 = lr + 16 * ((2 * lg + 1) & 3);

  // stage one 128x128 K/V tile into buffer BUF (8+8 gl_lds per thread)
#define STAGE_KV(T, BUF)                                                       \
  {                                                                            \
    const unsigned short* K_ = Kg + (size_t)(T)*128 * HD;                      \
    const unsigned short* V_ = Vg + (size_t)(T)*128;                           \
    _Pragma("unroll") for (int p = 0; p < 8; ++p) {                            \
      gl_lds16(K_ + (size_t)(p * 16 + srow0) * HD + ssc,                       \
               &Kl[BUF][p * 2048 + tid * 8]);                                  \
      gl_lds16(V_ + (size_t)(p * 16 + srow0) * SEQ + ssc,                      \
               &Vl[BUF][p * 2048 + tid * 8]);                                  \
    }                                                                          \
  }

  for (int sub = 0; sub < 2; ++sub) {
    const int xq = sub ? 15 - px : px;
    const int q0 = xq * 128;
    const int nt = xq + 1;  // KV-128 tiles

    bf16x8 qf0[4], qf1[4];
#pragma unroll
    for (int ks = 0; ks < 4; ++ks) {
      qf0[ks] = *(const bf16x8*)&Qg[(size_t)(q0 + wave * 32 + lr) * HD + ks * 32 + lg * 8];
      qf1[ks] = *(const bf16x8*)&Qg[(size_t)(q0 + wave * 32 + 16 + lr) * HD + ks * 32 + lg * 8];
    }

    f32x4 oacc0[8] = {}, oacc1[8] = {};
    float mraw0 = -1e30f, mraw1 = -1e30f;
    float lsum0 = 0.f, lsum1 = 0.f;

    STAGE_KV(0, 0);

    for (int t = 0; t < nt; ++t) {
      const int cur = t & 1;
      if (t + 1 < nt) {
        STAGE_KV(t + 1, cur ^ 1);
        asm volatile("s_waitcnt vmcnt(16)" ::: "memory");
      } else {
        asm volatile("s_waitcnt vmcnt(0)" ::: "memory");
      }
      __builtin_amdgcn_s_barrier();

      // ---- QK^T (swapped): sacc[mf][r] = S[kv=16mf+4lg+r][q] ----
      f32x4 sacc0[8] = {}, sacc1[8] = {};
      __builtin_amdgcn_s_setprio(1);
#pragma unroll
      for (int ks = 0; ks < 4; ++ks) {
        bf16x8 kf[8];
#pragma unroll
        for (int mf = 0; mf < 8; ++mf) {
          int row = mf * 16 + lr;
          kf[mf] = *(const bf16x8*)&Kl[cur][row * 128 + ((lg + ks * 4) ^ (lr & 7)) * 8];
        }
#pragma unroll
        for (int mf = 0; mf < 8; ++mf) {
          sacc0[mf] = __builtin_amdgcn_mfma_f32_16x16x32_bf16(kf[mf], qf0[ks], sacc0[mf], 0, 0, 0);
          sacc1[mf] = __builtin_amdgcn_mfma_f32_16x16x32_bf16(kf[mf], qf1[ks], sacc1[mf], 0, 0, 0);
        }
      }
      __builtin_amdgcn_s_setprio(0);

      if (t == nt - 1) {  // diagonal tile: causal mask (kv0 == q0 here)
#pragma unroll
        for (int mf = 0; mf < 8; ++mf)
#pragma unroll
          for (int r = 0; r < 4; ++r) {
            int kv = mf * 16 + lg * 4 + r;          // local kv == local q scale
            int qA = wave * 32 + lr;
            if (kv > qA) sacc0[mf][r] = -1e30f;
            if (kv > qA + 16) sacc1[mf][r] = -1e30f;
          }
      }

      // ---- row max per fragment ----
      float vm0 = -1e30f, vm1 = -1e30f;
#pragma unroll
      for (int mf = 0; mf < 8; ++mf) {
        vm0 = fmaxf(vm0, fmaxf(fmaxf(sacc0[mf][0], sacc0[mf][1]),
                               fmaxf(sacc0[mf][2], sacc0[mf][3])));
        vm1 = fmaxf(vm1, fmaxf(fmaxf(sacc1[mf][0], sacc1[mf][1]),
                               fmaxf(sacc1[mf][2], sacc1[mf][3])));
      }
      vm0 = fmaxf(vm0, __shfl_xor(vm0, 16));
      vm1 = fmaxf(vm1, __shfl_xor(vm1, 16));
      vm0 = fmaxf(vm0, __shfl_xor(vm0, 32));
      vm1 = fmaxf(vm1, __shfl_xor(vm1, 32));

      // ---- defer-max (T13) ----
      if (__any(fmaxf(vm0 - mraw0, vm1 - mraw1) > 60.0f)) {
        float nm0 = fmaxf(mraw0, vm0), nm1 = fmaxf(mraw1, vm1);
        float pf0 = exp2f((mraw0 - nm0) * C), pf1 = exp2f((mraw1 - nm1) * C);
#pragma unroll
        for (int r = 0; r < 4; ++r) {
          float f0 = __shfl(pf0, lg * 4 + r);
          float f1 = __shfl(pf1, lg * 4 + r);
#pragma unroll
          for (int nf8 = 0; nf8 < 8; ++nf8) {
            oacc0[nf8][r] *= f0;
            oacc1[nf8][r] *= f1;
          }
        }
        lsum0 *= pf0; lsum1 *= pf1;
        mraw0 = nm0; mraw1 = nm1;
      }
      const float mC0 = mraw0 * C, mC1 = mraw1 * C;

      // ---- exp + row sum ----
      float ss0 = 0.f, ss1 = 0.f;
#pragma unroll
      for (int mf = 0; mf < 8; ++mf)
#pragma unroll
        for (int r = 0; r < 4; ++r) {
          sacc0[mf][r] = exp2f(sacc0[mf][r] * C - mC0);
          sacc1[mf][r] = exp2f(sacc1[mf][r] * C - mC1);
          ss0 += sacc0[mf][r];
          ss1 += sacc1[mf][r];
        }
      ss0 += __shfl_xor(ss0, 16);
      ss1 += __shfl_xor(ss1, 16);
      ss0 += __shfl_xor(ss0, 32);
      ss1 += __shfl_xor(ss1, 32);
      lsum0 += ss0; lsum1 += ss1;

      // ---- T12: pack + in-register redistribution, 4 kv-32 chunks x 2 frags ----
      bf16x8 pa0[4], pa1[4];
      {
        unsigned pk0[8][2], pk1[8][2];
#pragma unroll
        for (int mf = 0; mf < 8; ++mf) {
          pk0[mf][0] = cvt_pk_bf16(sacc0[mf][0], sacc0[mf][1]);
          pk0[mf][1] = cvt_pk_bf16(sacc0[mf][2], sacc0[mf][3]);
          pk1[mf][0] = cvt_pk_bf16(sacc1[mf][0], sacc1[mf][1]);
          pk1[mf][1] = cvt_pk_bf16(sacc1[mf][2], sacc1[mf][3]);
        }
#define REDIST(PKV, LOW, OUT)                                                  \
        {                                                                      \
          unsigned a0 = __shfl((int)PKV[(LOW)][0], s0),                        \
                   b0 = __shfl((int)PKV[(LOW) + 1][0], s0);                    \
          unsigned a1 = __shfl((int)PKV[(LOW)][1], s0),                        \
                   b1 = __shfl((int)PKV[(LOW) + 1][1], s0);                    \
          unsigned a2 = __shfl((int)PKV[(LOW)][0], s1),                        \
                   b2 = __shfl((int)PKV[(LOW) + 1][0], s1);                    \
          unsigned a3 = __shfl((int)PKV[(LOW)][1], s1),                        \
                   b3 = __shfl((int)PKV[(LOW) + 1][1], s1);                    \
          u32x4 w = {hi ? b0 : a0, hi ? b1 : a1, hi ? b2 : a2, hi ? b3 : a3};  \
          OUT = __builtin_bit_cast(bf16x8, w);                                 \
        }
        REDIST(pk0, 0, pa0[0]); REDIST(pk0, 2, pa0[1]);
        REDIST(pk0, 4, pa0[2]); REDIST(pk0, 6, pa0[3]);
        REDIST(pk1, 0, pa1[0]); REDIST(pk1, 2, pa1[1]);
        REDIST(pk1, 4, pa1[2]); REDIST(pk1, 6, pa1[3]);
#undef REDIST
      }

      // ---- O += P . V (vf shared across fragments) ----
      __builtin_amdgcn_s_setprio(1);
#pragma unroll
      for (int c = 0; c < 4; ++c)
#pragma unroll
        for (int nf8 = 0; nf8 < 8; ++nf8) {
          int row = nf8 * 16 + lr;
          bf16x8 vf = *(const bf16x8*)&Vl[cur][row * 128 + ((c * 4 + lg) ^ (lr & 7)) * 8];
          oacc0[nf8] = __builtin_amdgcn_mfma_f32_16x16x32_bf16(pa0[c], vf, oacc0[nf8], 0, 0, 0);
          oacc1[nf8] = __builtin_amdgcn_mfma_f32_16x16x32_bf16(pa1[c], vf, oacc1[nf8], 0, 0, 0);
        }
      __builtin_amdgcn_s_setprio(0);

      __builtin_amdgcn_s_barrier();
    }

    // ---- normalize + store fp32, both fragments ----
#pragma unroll
    for (int r = 0; r < 4; ++r) {
      float li0 = 1.0f / __shfl(lsum0, lg * 4 + r);
      float li1 = 1.0f / __shfl(lsum1, lg * 4 + r);
      int qA = q0 + wave * 32 + lg * 4 + r;
      float* orowA = out + ((size_t)b * SEQ + qA) * DM + h * HD;
      float* orowB = orowA + (size_t)16 * DM;
#pragma unroll
      for (int nf8 = 0; nf8 < 8; ++nf8) {
        orowA[nf8 * 16 + lr] = oacc0[nf8][r] * li0;
        orowB[nf8 * 16 + lr] = oacc1[nf8][r] * li1;
      }
    }
    __builtin_amdgcn_s_barrier();  // all reads of LDS done before next subtile stages
  }
}

// ---------------- launcher ----------------
extern "C" void kernel_launch(void* const* d_in, const int* in_sizes, int n_in,
                              void* d_out, int out_size, void* d_ws, size_t ws_size,
                              hipStream_t stream) {
  const float* x  = (const float*)d_in[0];
  const float* Wq = (const float*)d_in[1];
  const float* Wk = (const float*)d_in[2];
  const float* Wv = (const float*)d_in[3];
  float* out = (float*)d_out;
  char* ws = (char*)d_ws;

  unsigned short* xb  = (unsigned short*)(ws);              // 4096x2048 bf16   (16 MB)
  unsigned short* wt  = (unsigned short*)(ws + 16777216);   // 3x 2048x2048 bf16 (24 MB)
  unsigned short* qb  = (unsigned short*)(ws + 41943040);   // [32][2048][128]  (16 MB)
  unsigned short* kb  = (unsigned short*)(ws + 58720256);   // [32][2048][128]  (16 MB)
  unsigned short* vtb = (unsigned short*)(ws + 75497472);   // [32][128][2048]  (16 MB)

  k_cvt_x<<<4096, 256, 0, stream>>>(x, xb);
  dim3 gw(32, 32, 3);
  k_cvt_w<<<gw, 256, 0, stream>>>(Wq, Wk, Wv, wt);
  k_qkv<<<768, 512, 0, stream>>>(xb, wt, qb, kb, vtb);
  k_attn<<<256, 256, 0, stream>>>(qb, kb, vtb, out);
}

// Round 9
// 213.057 us; speedup vs baseline: 1.4966x; 1.0171x over previous
//
#include <hip/hip_runtime.h>

#define DM   2048
#define SEQ  2048
#define NB   2
#define NH   16
#define HD   128

typedef __bf16 bf16x8 __attribute__((ext_vector_type(8)));
typedef float f32x4 __attribute__((ext_vector_type(4)));
typedef float f32x16 __attribute__((ext_vector_type(16)));
typedef unsigned short u16x4 __attribute__((ext_vector_type(4)));
typedef unsigned short u16x8 __attribute__((ext_vector_type(8)));
typedef unsigned int u32x4 __attribute__((ext_vector_type(4)));

__device__ __forceinline__ unsigned short f2b(float f) {
  return __builtin_bit_cast(unsigned short, (__bf16)f);
}

__device__ __forceinline__ unsigned cvt_pk_bf16(float lo, float hi) {
  unsigned r;
  asm("v_cvt_pk_bf16_f32 %0, %1, %2" : "=v"(r) : "v"(lo), "v"(hi));
  return r;
}

__device__ __forceinline__ void gl_lds16(const void* g, void* l) {
  __builtin_amdgcn_global_load_lds(
      (const __attribute__((address_space(1))) void*)g,
      (__attribute__((address_space(3))) void*)l, 16, 0, 0);
}

// ---------------- kernel 1: x fp32 -> bf16 ----------------
__global__ void k_cvt_x(const float* __restrict__ x, unsigned short* __restrict__ xb) {
  int i = blockIdx.x * 256 + threadIdx.x;
  const float4* src = (const float4*)x + (size_t)i * 2;
  float4 a = src[0], c = src[1];
  u16x8 o;
  o[0] = f2b(a.x); o[1] = f2b(a.y); o[2] = f2b(a.z); o[3] = f2b(a.w);
  o[4] = f2b(c.x); o[5] = f2b(c.y); o[6] = f2b(c.z); o[7] = f2b(c.w);
  *((u16x8*)xb + i) = o;
}

// ---------------- kernel 2: W fp32 [K][N] -> bf16 Wt [N][K] ----------------
__global__ void k_cvt_w(const float* __restrict__ Wq, const float* __restrict__ Wk,
                        const float* __restrict__ Wv, unsigned short* __restrict__ wts) {
  const float* W = blockIdx.z == 0 ? Wq : (blockIdx.z == 1 ? Wk : Wv);
  unsigned short* out = wts + (size_t)blockIdx.z * DM * DM;
  __shared__ unsigned short t[64 * 68];  // t[col][row]
  int c0 = blockIdx.x * 64, r0 = blockIdx.y * 64;
  int tr = threadIdx.x >> 4, tc = (threadIdx.x & 15) * 4;
#pragma unroll
  for (int p = 0; p < 4; ++p) {
    int r = p * 16 + tr;
    float4 v = *(const float4*)(W + (size_t)(r0 + r) * DM + c0 + tc);
    t[(tc + 0) * 68 + r] = f2b(v.x);
    t[(tc + 1) * 68 + r] = f2b(v.y);
    t[(tc + 2) * 68 + r] = f2b(v.z);
    t[(tc + 3) * 68 + r] = f2b(v.w);
  }
  __syncthreads();
#pragma unroll
  for (int p = 0; p < 4; ++p) {
    int c = p * 16 + tr;
    u16x4 o = *(const u16x4*)&t[c * 68 + tc];
    *(u16x4*)(out + (size_t)(c0 + c) * DM + r0 + tc) = o;
  }
}

// ---------------- kernel 3: QKV GEMM, 128x256 tile, 2-phase 8-wave ----------------
#define NT_ 32

#define ST_A(T)                                                                \
  if ((T) < NT_) {                                                             \
    const int ktS = (T);                                                       \
    const unsigned ab_ = (ktS & 1) * 8192u;                                    \
    gl_lds16(Ag + (size_t)srow * DM + ktS * 64 + sgcol, &smem[ab_ + bo0]);     \
    gl_lds16(Ag + (size_t)(64 + srow) * DM + ktS * 64 + sgcol,                 \
             &smem[ab_ + 4096 + bo0]);                                         \
  }

#define ST_B1(T)                                                               \
  if ((T) < NT_) {                                                             \
    const int ktS = (T);                                                       \
    const unsigned bb_ = 16384u + (ktS & 1) * 16384u;                          \
    gl_lds16(Bg + (size_t)grB * DM + ktS * 64 + sgcol, &smem[bb_ + bo1]);      \
    gl_lds16(Bg + (size_t)(grB + 128) * DM + ktS * 64 + sgcol,                 \
             &smem[bb_ + 8192 + bo1]);                                         \
  }

#define ST_B2(T)                                                               \
  if ((T) < NT_) {                                                             \
    const int ktS = (T);                                                       \
    const unsigned bb_ = 16384u + (ktS & 1) * 16384u;                          \
    gl_lds16(Bg + (size_t)(grB + 32) * DM + ktS * 64 + sgcol,                  \
             &smem[bb_ + 2048 + bo1]);                                         \
    gl_lds16(Bg + (size_t)(grB + 160) * DM + ktS * 64 + sgcol,                 \
             &smem[bb_ + 10240 + bo1]);                                        \
  }

#define DS_A_ALL                                                               \
  {                                                                            \
    _Pragma("unroll") for (int mf_ = 0; mf_ < 4; ++mf_) {                      \
      int row_ = wr * 64 + mf_ * 16 + lr;                                      \
      _Pragma("unroll") for (int ks_ = 0; ks_ < 2; ++ks_)                      \
        af[mf_][ks_] = *(const bf16x8*)&smem[ab + row_ * 64 +                  \
                                             (((lg + ks_ * 4) ^ (lr & 7)) * 8)];\
    }                                                                          \
  }

#define DS_B(NF, J)                                                            \
  {                                                                            \
    int row_ = wc * 64 + (NF)*16 + lr;                                         \
    _Pragma("unroll") for (int ks_ = 0; ks_ < 2; ++ks_)                        \
      bfr[J][ks_] = *(const bf16x8*)&smem[bb + row_ * 64 +                     \
                                          (((lg + ks_ * 4) ^ (lr & 7)) * 8)];  \
  }

#define MFMA_P(NFB)                                                            \
  {                                                                            \
    _Pragma("unroll") for (int mf_ = 0; mf_ < 4; ++mf_)                        \
    _Pragma("unroll") for (int j_ = 0; j_ < 2; ++j_)                           \
    _Pragma("unroll") for (int ks_ = 0; ks_ < 2; ++ks_)                        \
      acc[mf_][(NFB) + j_] = __builtin_amdgcn_mfma_f32_16x16x32_bf16(          \
          af[mf_][ks_], bfr[j_][ks_], acc[mf_][(NFB) + j_], 0, 0, 0);          \
  }

__global__ __launch_bounds__(512, 2) void k_qkv(
    const unsigned short* __restrict__ xb, const unsigned short* __restrict__ wts,
    unsigned short* __restrict__ qb, unsigned short* __restrict__ kb,
    unsigned short* __restrict__ vtb) {
  __shared__ unsigned short smem[49152];

  const int id = blockIdx.x;
  const int swz = (id & 7) * 96 + (id >> 3);
  const int z = swz >> 8;
  const int rem = swz & 255;
  const int m0 = (rem >> 3) * 128;
  const int n0 = (rem & 7) * 256;

  const unsigned short* Ag = xb + (size_t)m0 * DM;
  const unsigned short* Bg = wts + (size_t)z * DM * DM + (size_t)n0 * DM;

  const int tid = threadIdx.x;
  const int wave = tid >> 6, lane = tid & 63;
  const int lr = lane & 15, lg = lane >> 4;
  const int wr = wave >> 2, wc = wave & 3;
  const int srow = tid >> 3;
  const int sgcol = ((tid & 7) ^ (srow & 7)) * 8;
  const int grB = srow + (srow & 32);
  const unsigned bo0 = wave * 512u;
  const unsigned bo1 = wave * 512u + ((wave & 4) << 9);

  f32x4 acc[4][4] = {};
  bf16x8 af[4][2], bfr[2][2];

  ST_A(0); ST_B1(0); ST_B2(0); ST_A(1); ST_B1(1);
  asm volatile("s_waitcnt vmcnt(4)" ::: "memory");
  __builtin_amdgcn_s_barrier();

  for (int t = 0; t < NT_; ++t) {
    const unsigned ab = (t & 1) * 8192u;
    const unsigned bb = 16384u + (t & 1) * 16384u;

    DS_A_ALL;
    DS_B(0, 0); DS_B(1, 1);
    ST_B2(t + 1);
    asm volatile("s_waitcnt lgkmcnt(8)" ::: "memory");
    __builtin_amdgcn_s_barrier();
    asm volatile("s_waitcnt lgkmcnt(0)" ::: "memory");
    __builtin_amdgcn_sched_barrier(0);
    __builtin_amdgcn_s_setprio(1);
    MFMA_P(0);
    __builtin_amdgcn_s_setprio(0);
    __builtin_amdgcn_s_barrier();

    DS_B(2, 0); DS_B(3, 1);
    ST_A(t + 2); ST_B1(t + 2);
    if (t < NT_ - 2)
      asm volatile("s_waitcnt vmcnt(4)" ::: "memory");
    else
      asm volatile("s_waitcnt vmcnt(0)" ::: "memory");
    __builtin_amdgcn_s_barrier();
    asm volatile("s_waitcnt lgkmcnt(0)" ::: "memory");
    __builtin_amdgcn_sched_barrier(0);
    __builtin_amdgcn_s_setprio(1);
    MFMA_P(2);
    __builtin_amdgcn_s_setprio(0);
    __builtin_amdgcn_s_barrier();
  }

  if (z < 2) {
    unsigned short* out = z == 0 ? qb : kb;
#pragma unroll
    for (int mf = 0; mf < 4; ++mf)
#pragma unroll
      for (int nf = 0; nf < 4; ++nf) {
        int n = n0 + wc * 64 + nf * 16 + lr;
        int h = n >> 7, d = n & 127;
#pragma unroll
        for (int r = 0; r < 4; ++r) {
          int m = m0 + wr * 64 + mf * 16 + lg * 4 + r;
          int b = m >> 11, s = m & 2047;
          out[(((size_t)(b * NH + h)) * SEQ + s) * HD + d] = f2b(acc[mf][nf][r]);
        }
      }
  } else {
#pragma unroll
    for (int mf = 0; mf < 4; ++mf)
#pragma unroll
      for (int nf = 0; nf < 4; ++nf) {
        int dl = wc * 64 + nf * 16 + lr;
        int g = wr * 16 + mf * 4 + lg;
        int gs = g ^ ((dl & 7) << 2);
        u16x4 pk = {f2b(acc[mf][nf][0]), f2b(acc[mf][nf][1]),
                    f2b(acc[mf][nf][2]), f2b(acc[mf][nf][3])};
        *(u16x4*)&smem[dl * 128 + gs * 4] = pk;
      }
    __builtin_amdgcn_s_barrier();
    asm volatile("s_waitcnt lgkmcnt(0)" ::: "memory");
    int b = m0 >> 11, sbase = m0 & 2047;
#pragma unroll
    for (int p = 0; p < 8; ++p) {
      int f = p * 512 + tid;
      int dl = f >> 4, c8 = f & 15;
      int g0 = (2 * c8) ^ ((dl & 7) << 2);
      u16x8 v = *(const u16x8*)&smem[dl * 128 + g0 * 4];
      int n = n0 + dl;
      int h = n >> 7, d = n & 127;
      *(u16x8*)(vtb + (((size_t)(b * NH + h)) * HD + d) * SEQ + sbase + c8 * 8) = v;
    }
  }
}

// ---------------- kernel 4: causal flash attention, 32x32 in-register softmax ----------------
// 256 blocks (8 pairs x 32 bh, XCD-swizzled); 4 waves x 32 q-rows (QBLK=128).
// Pairs (x,15-x) -> uniform 34 KV-64 tiles/block. K/V dbuf LDS 64KB, vmcnt(8).
// Swapped QK^T via mfma_32x32x16: lane holds full P-column in regs -> in-lane softmax
// (1 shfl_xor(32) per stat); P->A-frags via 16 cvt_pk + 16 shfl_xor(32) + selects.
__global__ __launch_bounds__(256, 1) void k_attn(
    const unsigned short* __restrict__ qb, const unsigned short* __restrict__ kb,
    const unsigned short* __restrict__ vtb, float* __restrict__ out) {
  __shared__ unsigned short Kl[2][64 * 128];   // [kv][d], chunk-XOR swizzled (16KB x2)
  __shared__ unsigned short Vl[2][128 * 64];   // [d][kv], chunk-XOR swizzled (16KB x2)

  const int id = blockIdx.x;
  const int swz = (id & 7) * 32 + (id >> 3);   // bijective over 256
  const int bh = swz >> 3;
  const int px = swz & 7;
  const int b = bh >> 4, h = bh & 15;
  const int tid = threadIdx.x;
  const int wave = tid >> 6, lane = tid & 63;
  const int l31 = lane & 31, hi = lane >> 5;

  const unsigned short* Qg = qb + (size_t)bh * SEQ * HD;
  const unsigned short* Kg = kb + (size_t)bh * SEQ * HD;
  const unsigned short* Vg = vtb + (size_t)bh * HD * SEQ;
  const float C = 0.12751744155229827f;  // (1/sqrt(128)) * log2(e)

  // staging maps (linear LDS dest; inverse-swizzled global source)
  const int krow = tid >> 4, kc = tid & 15;
  const int ksw = (kc ^ (krow & 7)) * 8;
  const int vrow = tid >> 3, vc = tid & 7;
  const int vsw = (vc ^ (vrow & 7)) * 8;

#define STAGE_T(KV0, BUF)                                                      \
  {                                                                            \
    const unsigned short* K_ = Kg + (size_t)(KV0)*HD;                          \
    const unsigned short* V_ = Vg + (KV0);                                     \
    _Pragma("unroll") for (int p = 0; p < 4; ++p) {                            \
      gl_lds16(K_ + (size_t)(p * 16 + krow) * HD + ksw,                        \
               &Kl[BUF][(p * 256 + tid) * 8]);                                 \
      gl_lds16(V_ + (size_t)(p * 32 + vrow) * SEQ + vsw,                       \
               &Vl[BUF][(p * 256 + tid) * 8]);                                 \
    }                                                                          \
  }

  int g = 0;
  STAGE_T(0, 0);

  for (int sub = 0; sub < 2; ++sub) {
    const int x = sub ? 15 - px : px;
    const int q0 = x * 128;
    const int nt = 2 * x + 2;
    const int qw = q0 + wave * 32 + l31;   // this lane's q-row

    bf16x8 qf[8];
#pragma unroll
    for (int ks = 0; ks < 8; ++ks)
      qf[ks] = *(const bf16x8*)&Qg[(size_t)qw * HD + ks * 16 + hi * 8];

    f32x16 oacc[4] = {};   // [dblk]; lane: col d = dblk*32+l31, row q = crow(r,hi)
    float m_run = -1e30f, l_run = 0.f;

    for (int t = 0; t < nt; ++t, ++g) {
      const int cur = g & 1;
      if (t + 1 < nt) {
        STAGE_T((t + 1) * 64, cur ^ 1);
        asm volatile("s_waitcnt vmcnt(8)" ::: "memory");
      } else if (sub == 0) {
        STAGE_T(0, cur ^ 1);   // first tile of the paired subtile
        asm volatile("s_waitcnt vmcnt(8)" ::: "memory");
      } else {
        asm volatile("s_waitcnt vmcnt(0)" ::: "memory");
      }
      __builtin_amdgcn_s_barrier();

      // ---- S^T = K . Q^T : s0 = kv rows [0,32), s1 = [32,64); col q = l31 ----
      f32x16 s0 = {}, s1 = {};
      __builtin_amdgcn_s_setprio(1);
#pragma unroll
      for (int ks = 0; ks < 8; ++ks) {
        const int cch = ((2 * ks + hi) ^ (l31 & 7)) * 8;
        bf16x8 k0 = *(const bf16x8*)&Kl[cur][l31 * 128 + cch];
        bf16x8 k1 = *(const bf16x8*)&Kl[cur][(32 + l31) * 128 + cch];
        s0 = __builtin_amdgcn_mfma_f32_32x32x16_bf16(k0, qf[ks], s0, 0, 0, 0);
        s1 = __builtin_amdgcn_mfma_f32_32x32x16_bf16(k1, qf[ks], s1, 0, 0, 0);
      }
      __builtin_amdgcn_s_setprio(0);

      if (t >= nt - 2) {  // diagonal tiles: causal mask
        const int kv0 = t * 64;
#pragma unroll
        for (int r = 0; r < 16; ++r) {
          const int crow = (r & 3) + 8 * (r >> 2) + 4 * hi;
          if (kv0 + crow > qw) s0[r] = -1e30f;
          if (kv0 + 32 + crow > qw) s1[r] = -1e30f;
        }
      }

      // ---- in-lane row max + one cross-half combine ----
      float vm = -1e30f;
#pragma unroll
      for (int r = 0; r < 16; ++r) vm = fmaxf(vm, fmaxf(s0[r], s1[r]));
      vm = fmaxf(vm, __shfl_xor(vm, 32));

      // ---- defer-max (T13) ----
      if (__any(vm - m_run > 60.0f)) {
        const float nm = fmaxf(m_run, vm);
        const float pfac = exp2f((m_run - nm) * C);
#pragma unroll
        for (int r = 0; r < 16; ++r) {
          const int crow = (r & 3) + 8 * (r >> 2) + 4 * hi;
          const float f = __shfl(pfac, crow);
#pragma unroll
          for (int db = 0; db < 4; ++db) oacc[db][r] *= f;
        }
        l_run *= pfac;
        m_run = nm;
      }
      const float mC = m_run * C;

      // ---- exp + in-lane sum + one combine ----
      float ss = 0.f;
#pragma unroll
      for (int r = 0; r < 16; ++r) {
        s0[r] = exp2f(s0[r] * C - mC); ss += s0[r];
        s1[r] = exp2f(s1[r] * C - mC); ss += s1[r];
      }
      ss += __shfl_xor(ss, 32);
      l_run += ss;

      // ---- pack P (cvt_pk) + half-exchange (shfl_xor 32) -> PV A-frags ----
      unsigned u[16], xw[16];
#pragma unroll
      for (int i = 0; i < 8; ++i) {
        u[i] = cvt_pk_bf16(s0[2 * i], s0[2 * i + 1]);
        u[8 + i] = cvt_pk_bf16(s1[2 * i], s1[2 * i + 1]);
      }
#pragma unroll
      for (int i = 0; i < 16; ++i) xw[i] = (unsigned)__shfl_xor((int)u[i], 32);

      bf16x8 pf[4];
#pragma unroll
      for (int kb2 = 0; kb2 < 2; ++kb2) {
        const int o = kb2 * 8;
        u32x4 w0, w1;
        w0[0] = hi ? xw[o + 2] : u[o + 0];
        w0[1] = hi ? xw[o + 3] : u[o + 1];
        w0[2] = hi ? u[o + 2] : xw[o + 0];
        w0[3] = hi ? u[o + 3] : xw[o + 1];
        w1[0] = hi ? xw[o + 6] : u[o + 4];
        w1[1] = hi ? xw[o + 7] : u[o + 5];
        w1[2] = hi ? u[o + 6] : xw[o + 4];
        w1[3] = hi ? u[o + 7] : xw[o + 5];
        pf[kb2 * 2 + 0] = __builtin_bit_cast(bf16x8, w0);
        pf[kb2 * 2 + 1] = __builtin_bit_cast(bf16x8, w1);
      }

      // ---- O += P . V ----
      __builtin_amdgcn_s_setprio(1);
#pragma unroll
      for (int db = 0; db < 4; ++db) {
#pragma unroll
        for (int sl = 0; sl < 4; ++sl) {
          bf16x8 vf = *(const bf16x8*)&Vl[cur][(db * 32 + l31) * 64 +
                                              (((2 * sl + hi) ^ (l31 & 7)) * 8)];
          oacc[db] = __builtin_amdgcn_mfma_f32_32x32x16_bf16(pf[sl], vf, oacc[db], 0, 0, 0);
        }
      }
      __builtin_amdgcn_s_setprio(0);
      __builtin_amdgcn_s_barrier();
    }

    // ---- normalize + store fp32 ----
#pragma unroll
    for (int r = 0; r < 16; ++r) {
      const int crow = (r & 3) + 8 * (r >> 2) + 4 * hi;
      const float li = 1.0f / __shfl(l_run, crow);
      const int q = q0 + wave * 32 + crow;
      float* orow = out + ((size_t)b * SEQ + q) * DM + h * HD;
#pragma unroll
      for (int db = 0; db < 4; ++db)
        orow[db * 32 + l31] = oacc[db][r] * li;
    }
  }
}

// ---------------- launcher ----------------
extern "C" void kernel_launch(void* const* d_in, const int* in_sizes, int n_in,
                              void* d_out, int out_size, void* d_ws, size_t ws_size,
                              hipStream_t stream) {
  const float* x  = (const float*)d_in[0];
  const float* Wq = (const float*)d_in[1];
  const float* Wk = (const float*)d_in[2];
  const float* Wv = (const float*)d_in[3];
  float* out = (float*)d_out;
  char* ws = (char*)d_ws;

  unsigned short* xb  = (unsigned short*)(ws);              // 4096x2048 bf16   (16 MB)
  unsigned short* wt  = (unsigned short*)(ws + 16777216);   // 3x 2048x2048 bf16 (24 MB)
  unsigned short* qb  = (unsigned short*)(ws + 41943040);   // [32][2048][128]  (16 MB)
  unsigned short* kb  = (unsigned short*)(ws + 58720256);   // [32][2048][128]  (16 MB)
  unsigned short* vtb = (unsigned short*)(ws + 75497472);   // [32][128][2048]  (16 MB)

  k_cvt_x<<<4096, 256, 0, stream>>>(x, xb);
  dim3 gw(32, 32, 3);
  k_cvt_w<<<gw, 256, 0, stream>>>(Wq, Wk, Wv, wt);
  k_qkv<<<768, 512, 0, stream>>>(xb, wt, qb, kb, vtb);
  k_attn<<<256, 256, 0, stream>>>(qb, kb, vtb, out);
}